// Round 8
// baseline (422.736 us; speedup 1.0000x reference)
//
#include <hip/hip_runtime.h>
#include <hip/hip_bf16.h>
#include <math.h>

#define IN_DIM 128
#define OUT_DIM 128
#define BM 64

#define BSHIFT 9            // nodes per coarse bucket = 512
#define BNODES 512
#define CAP 9216            // pair capacity per coarse bucket (mean 8192, +11 sigma)
#define EPT 16              // edges per thread in coarse_scatter
#define NCHUNKS 8           // dim chunks: 16 dims = 32B bf16 each -> 3.2MB table

typedef short bf16x8s __attribute__((ext_vector_type(8)));
typedef float f32x4 __attribute__((ext_vector_type(4)));
typedef unsigned short u16;
typedef unsigned short u16x8 __attribute__((ext_vector_type(8)));

__device__ inline unsigned int rne_hi(float f) {
    unsigned int u = __float_as_uint(f);
    return u + 0x7fffu + ((u >> 16) & 1u);   // high 16 bits = RNE bf16
}
__device__ inline unsigned int pack_bf16x2(float lo, float hi) {
    return (rne_hi(lo) >> 16) | (rne_hi(hi) & 0xffff0000u);
}
__device__ inline float bf2f(u16 v) { return __uint_as_float(((unsigned)v) << 16); }

// ---------------------------------------------------------------------------
// K0: transpose + convert W [k][c] fp32 -> Wt bf16 [c][k]; also inits the
// coarse-bucket cursors.
// ---------------------------------------------------------------------------
__global__ void wt_kernel(const float* __restrict__ W, u16* __restrict__ Wt,
                          int* __restrict__ coarse_cur, int nbc)
{
    int k = blockIdx.x;
    int c = threadIdx.x;
    int ii = k * OUT_DIM + c;
    if (ii < nbc) coarse_cur[ii] = ii * CAP;
    float v = W[ii];
    Wt[c * IN_DIM + k] = (u16)(rne_hi(v) >> 16);
}

// ---------------------------------------------------------------------------
// K1: x = input @ W via bf16 MFMA; writes x in CHUNKED layout
// xc[c][node][16] (c = col/16) for L2-resident gathers; fused s_src/s_dst.
// ---------------------------------------------------------------------------
__global__ __launch_bounds__(256) void gemm_xw_kernel(
    const float* __restrict__ in, const u16* __restrict__ WtG,
    const float* __restrict__ a, u16* __restrict__ xc,
    float* __restrict__ ssrc, float* __restrict__ sdst, int N)
{
    __shared__ u16 Al[BM][IN_DIM + 8];
    __shared__ u16 Wl[OUT_DIM][IN_DIM + 8];

    const int tid  = threadIdx.x;
    const int lane = tid & 63;
    const int wave = tid >> 6;
    const int rl   = lane & 15;
    const int rgrp = lane >> 4;

    {
        int r = tid >> 1, c0 = (tid & 1) * 64;
        const uint4* src = (const uint4*)(WtG + r * IN_DIM + c0);
        uint4* dst = (uint4*)&Wl[r][c0];
#pragma unroll
        for (int u = 0; u < 8; u++) dst[u] = src[u];
    }
    const long long rowbase = (long long)blockIdx.x * BM;
    {
#pragma unroll
        for (int u = 0; u < 8; u++) {
            int idx = u * 256 + tid;
            int r = idx >> 5;
            int c = (idx & 31) * 4;
            long long gr = rowbase + r;
            if (gr >= N) gr = N - 1;
            float4 v = *(const float4*)(in + gr * IN_DIM + c);
            *(uint2*)&Al[r][c] = make_uint2(pack_bf16x2(v.x, v.y), pack_bf16x2(v.z, v.w));
        }
    }
    __syncthreads();

    f32x4 acc[8] = {};
#pragma unroll
    for (int ks = 0; ks < 4; ks++) {
        bf16x8s af = *(const bf16x8s*)&Al[wave * 16 + rl][ks * 32 + rgrp * 8];
#pragma unroll
        for (int cb = 0; cb < 8; cb++) {
            bf16x8s bf = *(const bf16x8s*)&Wl[cb * 16 + rl][ks * 32 + rgrp * 8];
            acc[cb] = __builtin_amdgcn_mfma_f32_16x16x32_bf16(af, bf, acc[cb], 0, 0, 0);
        }
    }

    float a_sv[8], a_dv[8];
#pragma unroll
    for (int cb = 0; cb < 8; cb++) {
        a_sv[cb] = a[rl + 16 * cb];
        a_dv[cb] = a[OUT_DIM + rl + 16 * cb];
    }
#pragma unroll
    for (int r = 0; r < 4; r++) {
        long long grow = rowbase + wave * 16 + rgrp * 4 + r;
        float ps = 0.f, pd = 0.f;
#pragma unroll
        for (int cb = 0; cb < 8; cb++) {
            float v = acc[cb][r];
            if (grow < N)
                xc[((size_t)cb * N + grow) * 16 + rl] = (u16)(rne_hi(v) >> 16);
            ps += v * a_sv[cb];
            pd += v * a_dv[cb];
        }
#pragma unroll
        for (int off = 1; off < 16; off <<= 1) {
            ps += __shfl_xor(ps, off);
            pd += __shfl_xor(pd, off);
        }
        if (rl == 0 && grow < N) { ssrc[grow] = ps; sdst[grow] = pd; }
    }
}

// ---------------------------------------------------------------------------
// K2: coarse scatter (as round 4).
// ---------------------------------------------------------------------------
__global__ __launch_bounds__(256) void coarse_scatter_kernel(
    const int* __restrict__ triple, int* __restrict__ coarse_cur,
    uint2* __restrict__ pairs, int E, int nbc)
{
    __shared__ int cnt[256];
    __shared__ int base[256];
    const int tid = threadIdx.x;
    const int cbase = blockIdx.x * (256 * EPT);

    cnt[tid] = 0;
    __syncthreads();

    int h[EPT], t[EPT], pos[EPT];
#pragma unroll
    for (int it = 0; it < EPT; ++it) {
        int idx = cbase + it * 256 + tid;
        if (idx < E) {
            h[it] = triple[3 * idx];
            t[it] = triple[3 * idx + 2];
            pos[it] = atomicAdd(&cnt[h[it] >> BSHIFT], 1);
        }
    }
    __syncthreads();
    if (tid < nbc && cnt[tid] > 0) base[tid] = atomicAdd(&coarse_cur[tid], cnt[tid]);
    __syncthreads();
#pragma unroll
    for (int it = 0; it < EPT; ++it) {
        int idx = cbase + it * 256 + tid;
        if (idx < E)
            pairs[base[h[it] >> BSHIFT] + pos[it]] = make_uint2((unsigned)h[it], (unsigned)t[it]);
    }
}

// ---------------------------------------------------------------------------
// K3: scan of bucket sizes -> dense CSR bucket bases
// ---------------------------------------------------------------------------
__global__ __launch_bounds__(256) void bucket_scan_kernel(
    const int* __restrict__ coarse_cur, int* __restrict__ bstart, int nbc)
{
    __shared__ int s[256];
    int tid = threadIdx.x;
    int sz = (tid < nbc) ? (coarse_cur[tid] - tid * CAP) : 0;
    s[tid] = sz;
    __syncthreads();
#pragma unroll
    for (int off = 1; off < 256; off <<= 1) {
        int v = (tid >= off) ? s[tid - off] : 0;
        __syncthreads();
        s[tid] += v;
        __syncthreads();
    }
    if (tid < nbc) bstart[tid] = s[tid] - sz;
}

// ---------------------------------------------------------------------------
// K4: per-bucket CSR build: writes startp and scatters t into ew[2*pos]
// (the (t,w) pair array; w filled by K5).
// ---------------------------------------------------------------------------
__global__ __launch_bounds__(512) void bucket_csr_kernel(
    const uint2* __restrict__ pairs, const int* __restrict__ coarse_cur,
    const int* __restrict__ bstart, int* __restrict__ startp,
    int* __restrict__ ew, int N, int E)
{
    __shared__ int cnt[BNODES];
    __shared__ int scn[BNODES];
    __shared__ int cursor[BNODES];
    const int b = blockIdx.x;
    const int tid = threadIdx.x;
    const int plo = b * CAP;
    const int psz = coarse_cur[b] - plo;
    const int obase = bstart[b];

    cnt[tid] = 0;
    __syncthreads();
    for (int j = tid; j < psz; j += BNODES)
        atomicAdd(&cnt[pairs[plo + j].x & (BNODES - 1)], 1);
    __syncthreads();
    scn[tid] = cnt[tid];
    __syncthreads();
#pragma unroll
    for (int off = 1; off < BNODES; off <<= 1) {
        int v = (tid >= off) ? scn[tid - off] : 0;
        __syncthreads();
        scn[tid] += v;
        __syncthreads();
    }
    const int excl = scn[tid] - cnt[tid];
    const int node = b * BNODES + tid;
    if (node < N) startp[node] = obase + excl;
    cursor[tid] = obase + excl;
    __syncthreads();
    for (int j = tid; j < psz; j += BNODES) {
        uint2 p = pairs[plo + j];
        int pos = atomicAdd(&cursor[p.x & (BNODES - 1)], 1);
        ew[2 * pos] = (int)p.y;
    }
    if (b == 0 && tid == 0) startp[N] = E;
}

// ---------------------------------------------------------------------------
// K5: per-node softmax weights. One wave/node (round-4 proven in-register
// path for deg<=64); writes w into ew[2*j+1]. sdst table (400KB) is
// L2-resident so gathers are cheap.
// ---------------------------------------------------------------------------
__global__ __launch_bounds__(256) void w_kernel(
    const float* __restrict__ ssrc, const float* __restrict__ sdst,
    const int* __restrict__ startp, int* __restrict__ ew, int N)
{
    const int wave = threadIdx.x >> 6;
    const int lane = threadIdx.x & 63;
    const int i = blockIdx.x * 4 + wave;
    if (i >= N) return;
    const int lo = startp[i];
    const int hi = startp[i + 1];
    const int deg = hi - lo;
    if (deg == 0) return;
    const float si = ssrc[i];

    if (deg <= 64) {
        int j = lo + lane;
        bool act = j < hi;
        int t = act ? ew[2 * j] : 0;
        float e = act ? si + sdst[t] : -INFINITY;
        e = (e > 0.f) ? e : 0.2f * e;
        float m = e;
#pragma unroll
        for (int off = 32; off; off >>= 1) m = fmaxf(m, __shfl_xor(m, off));
        float p = act ? __expf(e - m) : 0.f;
        float den = p;
#pragma unroll
        for (int off = 32; off; off >>= 1) den += __shfl_xor(den, off);
        if (act) ew[2 * j + 1] = __float_as_int(p / den);
    } else {
        float m = -INFINITY;
        for (int j = lo + lane; j < hi; j += 64) {
            float e = si + sdst[ew[2 * j]];
            e = (e > 0.f) ? e : 0.2f * e;
            m = fmaxf(m, e);
        }
#pragma unroll
        for (int off = 32; off; off >>= 1) m = fmaxf(m, __shfl_xor(m, off));
        float den = 0.f;
        for (int j = lo + lane; j < hi; j += 64) {
            float e = si + sdst[ew[2 * j]];
            e = (e > 0.f) ? e : 0.2f * e;
            den += __expf(e - m);
        }
#pragma unroll
        for (int off = 32; off; off >>= 1) den += __shfl_xor(den, off);
        const float invden = 1.f / den;
        for (int j = lo + lane; j < hi; j += 64) {
            float e = si + sdst[ew[2 * j]];
            e = (e > 0.f) ? e : 0.2f * e;
            ew[2 * j + 1] = __float_as_int(__expf(e - m) * invden);
        }
    }
}

// ---------------------------------------------------------------------------
// K6: chunked aggregation. blockIdx.y = dim-chunk c (16 dims, 32B rows,
// 3.2MB table -> L2-resident per XCD). One wave per node; 32 edge-slots x
// 2 half-lanes (16B each). Epilogue elu(agg + x_i) written per chunk.
// ---------------------------------------------------------------------------
__global__ __launch_bounds__(256) void chunk_agg_kernel(
    const u16* __restrict__ xc, const int* __restrict__ startp,
    const int* __restrict__ ew, float* __restrict__ out, int N)
{
    const int c    = blockIdx.y;
    const int wave = threadIdx.x >> 6;
    const int lane = threadIdx.x & 63;
    const int i = blockIdx.x * 4 + wave;
    if (i >= N) return;
    const int lo = startp[i];
    const int hi = startp[i + 1];
    const int slot = lane >> 1;
    const int half = lane & 1;
    const u16* __restrict__ xcc = xc + (size_t)c * N * 16;

    float acc[8];
#pragma unroll
    for (int d = 0; d < 8; d++) acc[d] = 0.f;

    for (int b = lo; b < hi; b += 32) {
        int ei = b + slot;
        if (ei < hi) {
            int2 p = *(const int2*)(ew + 2 * ei);
            float w = __int_as_float(p.y);
            u16x8 v = *(const u16x8*)(xcc + (size_t)p.x * 16 + half * 8);
#pragma unroll
            for (int d = 0; d < 8; d++) acc[d] += w * bf2f(v[d]);
        }
    }

    // reduce across the 32 slots (lane bits 1..5), halves stay separate
#pragma unroll
    for (int off = 2; off < 64; off <<= 1) {
#pragma unroll
        for (int d = 0; d < 8; d++) acc[d] += __shfl_xor(acc[d], off);
    }

    if (lane < 2) {
        u16x8 xi = *(const u16x8*)(xcc + (size_t)i * 16 + half * 8);
        float o[8];
#pragma unroll
        for (int d = 0; d < 8; d++) {
            float v = acc[d] + bf2f(xi[d]);
            o[d] = (v > 0.f) ? v : __expf(v) - 1.f;
        }
        float* dst = out + (size_t)i * OUT_DIM + c * 16 + half * 8;
        *(float4*)(dst)     = make_float4(o[0], o[1], o[2], o[3]);
        *(float4*)(dst + 4) = make_float4(o[4], o[5], o[6], o[7]);
    }
}

// ---------------------------------------------------------------------------
extern "C" void kernel_launch(void* const* d_in, const int* in_sizes, int n_in,
                              void* d_out, int out_size, void* d_ws, size_t ws_size,
                              hipStream_t stream)
{
    const float* input  = (const float*)d_in[0];
    const float* W      = (const float*)d_in[1];
    const float* a      = (const float*)d_in[2];
    const int*   triple = (const int*)d_in[3];
    const int N = in_sizes[0] / IN_DIM;
    const int E = in_sizes[3] / 3;
    float* out = (float*)d_out;

    const int NBC = (N + BNODES - 1) >> BSHIFT;   // coarse buckets (<=256)

    // workspace layout (all carves 16B-aligned)
    char* p = (char*)d_ws;
    auto carve = [&](size_t bytes) {
        char* q = p;
        p += (bytes + 15) & ~(size_t)15;
        return q;
    };
    u16*  xc        = (u16*)carve((size_t)N * OUT_DIM * sizeof(u16));     // chunked x
    u16*  Wt        = (u16*)carve((size_t)IN_DIM * OUT_DIM * sizeof(u16));
    float* ssrc     = (float*)carve((size_t)N * sizeof(float));
    float* sdst     = (float*)carve((size_t)N * sizeof(float));
    int*  startp    = (int*)carve((size_t)(N + 1) * sizeof(int));
    int*  coarse_cur= (int*)carve(256 * sizeof(int));
    int*  bstart    = (int*)carve(256 * sizeof(int));
    int*  ew        = (int*)carve((size_t)2 * E * sizeof(int));           // (t,w) pairs
    uint2* pairs    = (uint2*)carve((size_t)NBC * CAP * sizeof(uint2));

    const int NCH = (E + 256 * EPT - 1) / (256 * EPT);
    const int NODEB = (N + 3) / 4;

    wt_kernel<<<IN_DIM, OUT_DIM, 0, stream>>>(W, Wt, coarse_cur, NBC);
    gemm_xw_kernel<<<(N + BM - 1) / BM, 256, 0, stream>>>(input, Wt, a, xc, ssrc, sdst, N);
    coarse_scatter_kernel<<<NCH, 256, 0, stream>>>(triple, coarse_cur, pairs, E, NBC);
    bucket_scan_kernel<<<1, 256, 0, stream>>>(coarse_cur, bstart, NBC);
    bucket_csr_kernel<<<NBC, BNODES, 0, stream>>>(pairs, coarse_cur, bstart, startp, ew, N, E);
    w_kernel<<<NODEB, 256, 0, stream>>>(ssrc, sdst, startp, ew, N);
    chunk_agg_kernel<<<dim3(NODEB, NCHUNKS), 256, 0, stream>>>(xc, startp, ew, out, N);
}

// Round 9
// 153.771 us; speedup vs baseline: 2.7491x; 2.7491x over previous
//
#include <hip/hip_runtime.h>
#include <hip/hip_bf16.h>
#include <math.h>

#define IN_DIM 128
#define OUT_DIM 128
#define BM 64

#define BSHIFT 9            // nodes per coarse bucket = 512
#define BNODES 512
#define CAP 12288           // pair capacity per coarse bucket region
#define EPT 16              // edges per thread in coarse_scatter

typedef short bf16x8s __attribute__((ext_vector_type(8)));
typedef float f32x4 __attribute__((ext_vector_type(4)));
typedef unsigned short u16;
typedef unsigned short u16x8 __attribute__((ext_vector_type(8)));

__device__ inline unsigned int rne_hi(float f) {
    unsigned int u = __float_as_uint(f);
    return u + 0x7fffu + ((u >> 16) & 1u);   // high 16 bits = RNE bf16
}
__device__ inline unsigned int pack_bf16x2(float lo, float hi) {
    return (rne_hi(lo) >> 16) | (rne_hi(hi) & 0xffff0000u);
}
__device__ inline float bf2f(u16 v) { return __uint_as_float(((unsigned)v) << 16); }

// ---------------------------------------------------------------------------
// K0: transpose + convert W [k][c] fp32 -> Wt bf16 [c][k]; also inits the
// coarse-bucket cursors.
// ---------------------------------------------------------------------------
__global__ void wt_kernel(const float* __restrict__ W, u16* __restrict__ Wt,
                          int* __restrict__ coarse_cur, int nbc)
{
    int k = blockIdx.x;
    int c = threadIdx.x;
    int ii = k * OUT_DIM + c;
    if (ii < nbc) coarse_cur[ii] = ii * CAP;
    float v = W[ii];
    Wt[c * IN_DIM + k] = (u16)(rne_hi(v) >> 16);
}

// ---------------------------------------------------------------------------
// K1: x = input @ W via bf16 MFMA; writes x as bf16 row-major; fused scores.
// ---------------------------------------------------------------------------
__global__ __launch_bounds__(256) void gemm_xw_kernel(
    const float* __restrict__ in, const u16* __restrict__ WtG,
    const float* __restrict__ a, u16* __restrict__ xbf,
    float* __restrict__ ssrc, float* __restrict__ sdst, int N)
{
    __shared__ u16 Al[BM][IN_DIM + 8];
    __shared__ u16 Wl[OUT_DIM][IN_DIM + 8];

    const int tid  = threadIdx.x;
    const int lane = tid & 63;
    const int wave = tid >> 6;
    const int rl   = lane & 15;
    const int rgrp = lane >> 4;

    {
        int r = tid >> 1, c0 = (tid & 1) * 64;
        const uint4* src = (const uint4*)(WtG + r * IN_DIM + c0);
        uint4* dst = (uint4*)&Wl[r][c0];
#pragma unroll
        for (int u = 0; u < 8; u++) dst[u] = src[u];
    }
    const long long rowbase = (long long)blockIdx.x * BM;
    {
#pragma unroll
        for (int u = 0; u < 8; u++) {
            int idx = u * 256 + tid;
            int r = idx >> 5;
            int c = (idx & 31) * 4;
            long long gr = rowbase + r;
            if (gr >= N) gr = N - 1;
            float4 v = *(const float4*)(in + gr * IN_DIM + c);
            *(uint2*)&Al[r][c] = make_uint2(pack_bf16x2(v.x, v.y), pack_bf16x2(v.z, v.w));
        }
    }
    __syncthreads();

    f32x4 acc[8] = {};
#pragma unroll
    for (int ks = 0; ks < 4; ks++) {
        bf16x8s af = *(const bf16x8s*)&Al[wave * 16 + rl][ks * 32 + rgrp * 8];
#pragma unroll
        for (int cb = 0; cb < 8; cb++) {
            bf16x8s bf = *(const bf16x8s*)&Wl[cb * 16 + rl][ks * 32 + rgrp * 8];
            acc[cb] = __builtin_amdgcn_mfma_f32_16x16x32_bf16(af, bf, acc[cb], 0, 0, 0);
        }
    }

    float a_sv[8], a_dv[8];
#pragma unroll
    for (int cb = 0; cb < 8; cb++) {
        a_sv[cb] = a[rl + 16 * cb];
        a_dv[cb] = a[OUT_DIM + rl + 16 * cb];
    }
#pragma unroll
    for (int r = 0; r < 4; r++) {
        long long grow = rowbase + wave * 16 + rgrp * 4 + r;
        float ps = 0.f, pd = 0.f;
#pragma unroll
        for (int cb = 0; cb < 8; cb++) {
            float v = acc[cb][r];
            if (grow < N) xbf[grow * OUT_DIM + rl + 16 * cb] = (u16)(rne_hi(v) >> 16);
            ps += v * a_sv[cb];
            pd += v * a_dv[cb];
        }
#pragma unroll
        for (int off = 1; off < 16; off <<= 1) {
            ps += __shfl_xor(ps, off);
            pd += __shfl_xor(pd, off);
        }
        if (rl == 0 && grow < N) { ssrc[grow] = ps; sdst[grow] = pd; }
    }
}

// ---------------------------------------------------------------------------
// K2: coarse scatter (proven round-4 version).
// ---------------------------------------------------------------------------
__global__ __launch_bounds__(256) void coarse_scatter_kernel(
    const int* __restrict__ triple, int* __restrict__ coarse_cur,
    uint2* __restrict__ pairs, int E, int nbc)
{
    __shared__ int cnt[256];
    __shared__ int base[256];
    const int tid = threadIdx.x;
    const int cbase = blockIdx.x * (256 * EPT);

    cnt[tid] = 0;
    __syncthreads();

    int h[EPT], t[EPT], pos[EPT];
#pragma unroll
    for (int it = 0; it < EPT; ++it) {
        int idx = cbase + it * 256 + tid;
        if (idx < E) {
            h[it] = triple[3 * idx];
            t[it] = triple[3 * idx + 2];
            pos[it] = atomicAdd(&cnt[h[it] >> BSHIFT], 1);
        }
    }
    __syncthreads();
    if (tid < nbc && cnt[tid] > 0) base[tid] = atomicAdd(&coarse_cur[tid], cnt[tid]);
    __syncthreads();
#pragma unroll
    for (int it = 0; it < EPT; ++it) {
        int idx = cbase + it * 256 + tid;
        if (idx < E)
            pairs[base[h[it] >> BSHIFT] + pos[it]] = make_uint2((unsigned)h[it], (unsigned)t[it]);
    }
}

// ---------------------------------------------------------------------------
// K3: scan of bucket sizes -> dense CSR bucket bases
// ---------------------------------------------------------------------------
__global__ __launch_bounds__(256) void bucket_scan_kernel(
    const int* __restrict__ coarse_cur, int* __restrict__ bstart, int nbc)
{
    __shared__ int s[256];
    int tid = threadIdx.x;
    int sz = (tid < nbc) ? (coarse_cur[tid] - tid * CAP) : 0;
    s[tid] = sz;
    __syncthreads();
#pragma unroll
    for (int off = 1; off < 256; off <<= 1) {
        int v = (tid >= off) ? s[tid - off] : 0;
        __syncthreads();
        s[tid] += v;
        __syncthreads();
    }
    if (tid < nbc) bstart[tid] = s[tid] - sz;
}

// ---------------------------------------------------------------------------
// K4: per-bucket CSR build (proven round-4 version).
// ---------------------------------------------------------------------------
__global__ __launch_bounds__(512) void bucket_csr_kernel(
    const uint2* __restrict__ pairs, const int* __restrict__ coarse_cur,
    const int* __restrict__ bstart, int* __restrict__ startp,
    int* __restrict__ edge_t, int N, int E)
{
    __shared__ int cnt[BNODES];
    __shared__ int scn[BNODES];
    __shared__ int cursor[BNODES];
    const int b = blockIdx.x;
    const int tid = threadIdx.x;
    const int plo = b * CAP;
    const int psz = coarse_cur[b] - plo;
    const int obase = bstart[b];

    cnt[tid] = 0;
    __syncthreads();
    for (int j = tid; j < psz; j += BNODES)
        atomicAdd(&cnt[pairs[plo + j].x & (BNODES - 1)], 1);
    __syncthreads();
    scn[tid] = cnt[tid];
    __syncthreads();
#pragma unroll
    for (int off = 1; off < BNODES; off <<= 1) {
        int v = (tid >= off) ? scn[tid - off] : 0;
        __syncthreads();
        scn[tid] += v;
        __syncthreads();
    }
    const int excl = scn[tid] - cnt[tid];
    const int node = b * BNODES + tid;
    if (node < N) startp[node] = obase + excl;
    cursor[tid] = obase + excl;
    __syncthreads();
    for (int j = tid; j < psz; j += BNODES) {
        uint2 p = pairs[plo + j];
        int pos = atomicAdd(&cursor[p.x & (BNODES - 1)], 1);
        edge_t[pos] = (int)p.y;
    }
    if (b == 0 && tid == 0) startp[N] = E;
}

// ---------------------------------------------------------------------------
// K5: per-node softmax aggregation. One wave/node; 8 edge-groups x 8 lanes;
// lane (k = lane>>3) owns dims [16k,16k+16). deg<=32 fast path (99.98% of
// nodes): 4 fully-unrolled guarded 8-edge batches, ALL gathers issued before
// any FMA (up to 8 outstanding 16B loads/lane), compile-time reg indices.
// Wave-uniform batch guards; tail lanes gather row 0 with w=0 (harmless).
// ---------------------------------------------------------------------------
__global__ __launch_bounds__(256) void aggregate_kernel(
    const u16* __restrict__ xbf, const float* __restrict__ ssrc,
    const float* __restrict__ sdst, const int* __restrict__ startp,
    const int* __restrict__ edge_t, float* __restrict__ out, int N)
{
    const int wave = threadIdx.x >> 6;
    const int lane = threadIdx.x & 63;
    const int i = blockIdx.x * 4 + wave;
    if (i >= N) return;
    const int lo = startp[i];
    const int hi = startp[i + 1];
    const int deg = hi - lo;
    const float si = ssrc[i];
    const int k = lane >> 3;   // dim-slice 0..7
    const int g = lane & 7;    // edge-group 0..7

    float acc[16];
#pragma unroll
    for (int d = 0; d < 16; d++) acc[d] = 0.f;

    if (deg == 0) {
        // acc stays 0 -> out = elu(x_i)
    } else if (deg <= 64) {
        // ---- single-pass softmax in registers ----
        int j = lo + lane;
        bool act = j < hi;
        int t = act ? edge_t[j] : 0;
        float e = act ? si + sdst[t] : -INFINITY;
        e = (e > 0.f) ? e : 0.2f * e;
        float m = e;
#pragma unroll
        for (int off = 32; off; off >>= 1) m = fmaxf(m, __shfl_xor(m, off));
        float p = act ? __expf(e - m) : 0.f;
        float den = p;
#pragma unroll
        for (int off = 32; off; off >>= 1) den += __shfl_xor(den, off);
        float w = p / den;   // inactive lanes: 0/den = 0

        const u16* xk = xbf + (size_t)k * 16;

        if (deg <= 32) {
            // ---- 4 unrolled batches: issue ALL loads, then ALL FMAs ----
            int tt0, tt1, tt2, tt3;
            float ww0, ww1, ww2, ww3;
            u16x8 a0, b0, a1, b1, a2, b2, a3, b3;

            tt0 = __shfl(t, g);          ww0 = __shfl(w, g);
            {
                const u16x8* s = (const u16x8*)(xk + (size_t)tt0 * OUT_DIM);
                a0 = s[0]; b0 = s[1];
            }
            if (deg > 8) {
                tt1 = __shfl(t, 8 + g);  ww1 = __shfl(w, 8 + g);
                const u16x8* s = (const u16x8*)(xk + (size_t)tt1 * OUT_DIM);
                a1 = s[0]; b1 = s[1];
            }
            if (deg > 16) {
                tt2 = __shfl(t, 16 + g); ww2 = __shfl(w, 16 + g);
                const u16x8* s = (const u16x8*)(xk + (size_t)tt2 * OUT_DIM);
                a2 = s[0]; b2 = s[1];
            }
            if (deg > 24) {
                tt3 = __shfl(t, 24 + g); ww3 = __shfl(w, 24 + g);
                const u16x8* s = (const u16x8*)(xk + (size_t)tt3 * OUT_DIM);
                a3 = s[0]; b3 = s[1];
            }

#pragma unroll
            for (int d = 0; d < 8; d++) {
                acc[d]     += ww0 * bf2f(a0[d]);
                acc[8 + d] += ww0 * bf2f(b0[d]);
            }
            if (deg > 8) {
#pragma unroll
                for (int d = 0; d < 8; d++) {
                    acc[d]     += ww1 * bf2f(a1[d]);
                    acc[8 + d] += ww1 * bf2f(b1[d]);
                }
            }
            if (deg > 16) {
#pragma unroll
                for (int d = 0; d < 8; d++) {
                    acc[d]     += ww2 * bf2f(a2[d]);
                    acc[8 + d] += ww2 * bf2f(b2[d]);
                }
            }
            if (deg > 24) {
#pragma unroll
                for (int d = 0; d < 8; d++) {
                    acc[d]     += ww3 * bf2f(a3[d]);
                    acc[8 + d] += ww3 * bf2f(b3[d]);
                }
            }
        } else {
            // deg in (32,64]: rare (~0.02% of nodes) — guarded batch loop
            int nit = (deg + 7) >> 3;
            for (int it = 0; it < nit; ++it) {
                int ei = it * 8 + g;
                int tt = __shfl(t, ei);
                float ww = __shfl(w, ei);
                if (ei < deg) {
                    const u16x8* src = (const u16x8*)(xk + (size_t)tt * OUT_DIM);
                    u16x8 v0 = src[0], v1 = src[1];
#pragma unroll
                    for (int d = 0; d < 8; d++) {
                        acc[d]     += ww * bf2f(v0[d]);
                        acc[8 + d] += ww * bf2f(v1[d]);
                    }
                }
            }
        }
    } else {
        // ---- general path (deg > 64): strided passes ----
        float m = -INFINITY;
        for (int j = lo + lane; j < hi; j += 64) {
            int t = edge_t[j];
            float e = si + sdst[t];
            e = (e > 0.f) ? e : 0.2f * e;
            m = fmaxf(m, e);
        }
#pragma unroll
        for (int off = 32; off; off >>= 1) m = fmaxf(m, __shfl_xor(m, off));
        float den = 0.f;
        for (int j = lo + lane; j < hi; j += 64) {
            int t = edge_t[j];
            float e = si + sdst[t];
            e = (e > 0.f) ? e : 0.2f * e;
            den += __expf(e - m);
        }
#pragma unroll
        for (int off = 32; off; off >>= 1) den += __shfl_xor(den, off);
        const float invden = 1.f / den;

        for (int jj = lo; jj < hi; jj += 8) {
            int ei = jj + g;
            if (ei < hi) {
                int tt = edge_t[ei];
                float e = si + sdst[tt];
                e = (e > 0.f) ? e : 0.2f * e;
                float ww = __expf(e - m) * invden;
                const u16x8* src = (const u16x8*)(xbf + (size_t)tt * OUT_DIM + k * 16);
                u16x8 v0 = src[0], v1 = src[1];
#pragma unroll
                for (int d = 0; d < 8; d++) {
                    acc[d]     += ww * bf2f(v0[d]);
                    acc[8 + d] += ww * bf2f(v1[d]);
                }
            }
        }
    }

    // ---- cross-group reduce (groups differ in low 3 lane bits) ----
#pragma unroll
    for (int off = 1; off < 8; off <<= 1) {
#pragma unroll
        for (int d = 0; d < 16; d++) acc[d] += __shfl_xor(acc[d], off);
    }

    // ---- epilogue from 8 lanes (g==0): elu(acc + x_i) ----
    if (g == 0) {
        const u16x8* xr = (const u16x8*)(xbf + (size_t)i * OUT_DIM + k * 16);
        u16x8 x0 = xr[0], x1 = xr[1];
        float o[16];
#pragma unroll
        for (int d = 0; d < 8; d++) {
            o[d]     = acc[d]     + bf2f(x0[d]);
            o[8 + d] = acc[8 + d] + bf2f(x1[d]);
        }
#pragma unroll
        for (int d = 0; d < 16; d++) o[d] = (o[d] > 0.f) ? o[d] : __expf(o[d]) - 1.f;
        float* dst = out + (size_t)i * OUT_DIM + k * 16;
#pragma unroll
        for (int u = 0; u < 4; u++)
            *(float4*)(dst + u * 4) = make_float4(o[u*4], o[u*4+1], o[u*4+2], o[u*4+3]);
    }
}

// ---------------------------------------------------------------------------
extern "C" void kernel_launch(void* const* d_in, const int* in_sizes, int n_in,
                              void* d_out, int out_size, void* d_ws, size_t ws_size,
                              hipStream_t stream)
{
    const float* input  = (const float*)d_in[0];
    const float* W      = (const float*)d_in[1];
    const float* a      = (const float*)d_in[2];
    const int*   triple = (const int*)d_in[3];
    const int N = in_sizes[0] / IN_DIM;
    const int E = in_sizes[3] / 3;
    float* out = (float*)d_out;

    const int NBC = (N + BNODES - 1) >> BSHIFT;   // coarse buckets (<=256)

    // workspace layout
    char* p = (char*)d_ws;
    auto carve = [&](size_t bytes) {
        char* q = p;
        p += (bytes + 15) & ~(size_t)15;
        return q;
    };
    u16*  xbf       = (u16*)carve((size_t)N * OUT_DIM * sizeof(u16));
    u16*  Wt        = (u16*)carve((size_t)IN_DIM * OUT_DIM * sizeof(u16));
    float* ssrc     = (float*)carve((size_t)N * sizeof(float));
    float* sdst     = (float*)carve((size_t)N * sizeof(float));
    int*  startp    = (int*)carve((size_t)(N + 1) * sizeof(int));
    int*  coarse_cur= (int*)carve(256 * sizeof(int));
    int*  bstart    = (int*)carve(256 * sizeof(int));
    int*  edge_t    = (int*)carve((size_t)E * sizeof(int));
    uint2* pairs    = (uint2*)carve((size_t)NBC * CAP * sizeof(uint2));

    const int NCH = (E + 256 * EPT - 1) / (256 * EPT);

    wt_kernel<<<IN_DIM, OUT_DIM, 0, stream>>>(W, Wt, coarse_cur, NBC);
    gemm_xw_kernel<<<(N + BM - 1) / BM, 256, 0, stream>>>(input, Wt, a, xbf, ssrc, sdst, N);
    coarse_scatter_kernel<<<NCH, 256, 0, stream>>>(triple, coarse_cur, pairs, E, NBC);
    bucket_scan_kernel<<<1, 256, 0, stream>>>(coarse_cur, bstart, NBC);
    bucket_csr_kernel<<<NBC, BNODES, 0, stream>>>(pairs, coarse_cur, bstart, startp, edge_t, N, E);
    aggregate_kernel<<<(N + 3) / 4, 256, 0, stream>>>(xbf, ssrc, sdst, startp, edge_t, out, N);
}

// Round 10
// 140.761 us; speedup vs baseline: 3.0032x; 1.0924x over previous
//
#include <hip/hip_runtime.h>
#include <hip/hip_bf16.h>
#include <math.h>

#define IN_DIM 128
#define OUT_DIM 128
#define BM 64

#define BSHIFT 9            // nodes per coarse bucket = 512
#define BNODES 512
#define CAP 12288           // pair capacity per coarse bucket region
#define EPT 16              // edges per thread in coarse_scatter

typedef short bf16x8s __attribute__((ext_vector_type(8)));
typedef float f32x4 __attribute__((ext_vector_type(4)));
typedef unsigned short u16;
typedef unsigned short u16x8 __attribute__((ext_vector_type(8)));

__device__ inline unsigned int rne_hi(float f) {
    unsigned int u = __float_as_uint(f);
    return u + 0x7fffu + ((u >> 16) & 1u);   // high 16 bits = RNE bf16
}
__device__ inline unsigned int pack_bf16x2(float lo, float hi) {
    return (rne_hi(lo) >> 16) | (rne_hi(hi) & 0xffff0000u);
}
__device__ inline float bf2f(u16 v) { return __uint_as_float(((unsigned)v) << 16); }

// ---------------------------------------------------------------------------
// K0: transpose + convert W [k][c] fp32 -> Wt bf16 [c][k]
// ---------------------------------------------------------------------------
__global__ void wt_kernel(const float* __restrict__ W, u16* __restrict__ Wt)
{
    int k = blockIdx.x;
    int c = threadIdx.x;
    Wt[c * IN_DIM + k] = (u16)(rne_hi(W[k * OUT_DIM + c]) >> 16);
}

// ---------------------------------------------------------------------------
// K1: FUSED gemm + coarse_scatter. Blocks [0, nScat) run the edge scatter
// (independent of gemm); blocks [nScat, nScat+nGemm) run the MFMA gemm.
// coarse_cur must be zeroed beforehand (memset); pair region b starts at
// b*CAP, so base = tid*CAP + atomicAdd(size).
// ---------------------------------------------------------------------------
__global__ __launch_bounds__(256) void gemm_scatter_kernel(
    const float* __restrict__ in, const u16* __restrict__ WtG,
    const float* __restrict__ a, u16* __restrict__ xbf,
    float* __restrict__ ssrc, float* __restrict__ sdst,
    const int* __restrict__ triple, int* __restrict__ coarse_cur,
    uint2* __restrict__ pairs, int N, int E, int nbc, int nScat)
{
    const int tid = threadIdx.x;

    if ((int)blockIdx.x < nScat) {
        // ================= coarse scatter =================
        __shared__ int cnt[256];
        __shared__ int base[256];
        const int cbase = blockIdx.x * (256 * EPT);

        cnt[tid] = 0;
        __syncthreads();

        int h[EPT], t[EPT], pos[EPT];
#pragma unroll
        for (int it = 0; it < EPT; ++it) {
            int idx = cbase + it * 256 + tid;
            if (idx < E) {
                h[it] = triple[3 * idx];
                t[it] = triple[3 * idx + 2];
                pos[it] = atomicAdd(&cnt[h[it] >> BSHIFT], 1);
            }
        }
        __syncthreads();
        if (tid < nbc && cnt[tid] > 0)
            base[tid] = tid * CAP + atomicAdd(&coarse_cur[tid], cnt[tid]);
        __syncthreads();
#pragma unroll
        for (int it = 0; it < EPT; ++it) {
            int idx = cbase + it * 256 + tid;
            if (idx < E)
                pairs[base[h[it] >> BSHIFT] + pos[it]] =
                    make_uint2((unsigned)h[it], (unsigned)t[it]);
        }
        return;
    }

    // ================= gemm =================
    __shared__ u16 Al[BM][IN_DIM + 8];
    __shared__ u16 Wl[OUT_DIM][IN_DIM + 8];

    const int gb   = blockIdx.x - nScat;
    const int lane = tid & 63;
    const int wave = tid >> 6;
    const int rl   = lane & 15;
    const int rgrp = lane >> 4;

    {
        int r = tid >> 1, c0 = (tid & 1) * 64;
        const uint4* src = (const uint4*)(WtG + r * IN_DIM + c0);
        uint4* dst = (uint4*)&Wl[r][c0];
#pragma unroll
        for (int u = 0; u < 8; u++) dst[u] = src[u];
    }
    const long long rowbase = (long long)gb * BM;
    {
#pragma unroll
        for (int u = 0; u < 8; u++) {
            int idx = u * 256 + tid;
            int r = idx >> 5;
            int c = (idx & 31) * 4;
            long long gr = rowbase + r;
            if (gr >= N) gr = N - 1;
            float4 v = *(const float4*)(in + gr * IN_DIM + c);
            *(uint2*)&Al[r][c] = make_uint2(pack_bf16x2(v.x, v.y), pack_bf16x2(v.z, v.w));
        }
    }
    __syncthreads();

    f32x4 acc[8] = {};
#pragma unroll
    for (int ks = 0; ks < 4; ks++) {
        bf16x8s af = *(const bf16x8s*)&Al[wave * 16 + rl][ks * 32 + rgrp * 8];
#pragma unroll
        for (int cb = 0; cb < 8; cb++) {
            bf16x8s bf = *(const bf16x8s*)&Wl[cb * 16 + rl][ks * 32 + rgrp * 8];
            acc[cb] = __builtin_amdgcn_mfma_f32_16x16x32_bf16(af, bf, acc[cb], 0, 0, 0);
        }
    }

    float a_sv[8], a_dv[8];
#pragma unroll
    for (int cb = 0; cb < 8; cb++) {
        a_sv[cb] = a[rl + 16 * cb];
        a_dv[cb] = a[OUT_DIM + rl + 16 * cb];
    }
#pragma unroll
    for (int r = 0; r < 4; r++) {
        long long grow = rowbase + wave * 16 + rgrp * 4 + r;
        float ps = 0.f, pd = 0.f;
#pragma unroll
        for (int cb = 0; cb < 8; cb++) {
            float v = acc[cb][r];
            if (grow < N) xbf[grow * OUT_DIM + rl + 16 * cb] = (u16)(rne_hi(v) >> 16);
            ps += v * a_sv[cb];
            pd += v * a_dv[cb];
        }
#pragma unroll
        for (int off = 1; off < 16; off <<= 1) {
            ps += __shfl_xor(ps, off);
            pd += __shfl_xor(pd, off);
        }
        if (rl == 0 && grow < N) { ssrc[grow] = ps; sdst[grow] = pd; }
    }
}

// ---------------------------------------------------------------------------
// K2: per-bucket CSR build with INLINE scan of bucket sizes (coarse_cur now
// holds sizes directly). One block per coarse bucket.
// ---------------------------------------------------------------------------
__global__ __launch_bounds__(512) void bucket_csr_kernel(
    const uint2* __restrict__ pairs, const int* __restrict__ coarse_cur,
    int* __restrict__ startp, int* __restrict__ edge_t, int N, int E, int nbc)
{
    __shared__ int cnt[BNODES];
    __shared__ int scn[BNODES];
    __shared__ int cursor[BNODES];
    __shared__ int bsum[256];
    const int b = blockIdx.x;
    const int tid = threadIdx.x;
    const int plo = b * CAP;
    const int psz = coarse_cur[b];

    // ---- inline 256-wide inclusive scan of bucket sizes ----
    if (tid < 256) bsum[tid] = (tid < nbc) ? coarse_cur[tid] : 0;
    __syncthreads();
#pragma unroll
    for (int off = 1; off < 256; off <<= 1) {
        int v = 0;
        if (tid < 256 && tid >= off) v = bsum[tid - off];
        __syncthreads();
        if (tid < 256 && tid >= off) bsum[tid] += v;
        __syncthreads();
    }
    const int obase = bsum[b] - psz;

    cnt[tid] = 0;
    __syncthreads();
    for (int j = tid; j < psz; j += BNODES)
        atomicAdd(&cnt[pairs[plo + j].x & (BNODES - 1)], 1);
    __syncthreads();
    scn[tid] = cnt[tid];
    __syncthreads();
#pragma unroll
    for (int off = 1; off < BNODES; off <<= 1) {
        int v = (tid >= off) ? scn[tid - off] : 0;
        __syncthreads();
        scn[tid] += v;
        __syncthreads();
    }
    const int excl = scn[tid] - cnt[tid];
    const int node = b * BNODES + tid;
    if (node < N) startp[node] = obase + excl;
    cursor[tid] = obase + excl;
    __syncthreads();
    for (int j = tid; j < psz; j += BNODES) {
        uint2 p = pairs[plo + j];
        int pos = atomicAdd(&cursor[p.x & (BNODES - 1)], 1);
        edge_t[pos] = (int)p.y;
    }
    if (b == 0 && tid == 0) startp[N] = E;
}

// ---------------------------------------------------------------------------
// K3: per-node softmax aggregation. One wave/node; 4 edge-groups x 16 lanes.
// Lane (eg, j16) handles edge-slot eg of each 4-edge batch and the contiguous
// 16B chunk j16 of the row: ONE load instruction per edge covering the 256B
// row with exactly 4 cache-line touches (vs 2 instr / 8 touches before).
// ---------------------------------------------------------------------------
__global__ __launch_bounds__(256) void aggregate_kernel(
    const u16* __restrict__ xbf, const float* __restrict__ ssrc,
    const float* __restrict__ sdst, const int* __restrict__ startp,
    const int* __restrict__ edge_t, float* __restrict__ out, int N)
{
    const int wave = threadIdx.x >> 6;
    const int lane = threadIdx.x & 63;
    const int i = blockIdx.x * 4 + wave;
    if (i >= N) return;
    const int lo = startp[i];
    const int hi = startp[i + 1];
    const int deg = hi - lo;
    const float si = ssrc[i];
    const int eg  = lane >> 4;   // edge slot 0..3
    const int j16 = lane & 15;   // 16B chunk 0..15

    float acc[8];
#pragma unroll
    for (int d = 0; d < 8; d++) acc[d] = 0.f;

    if (deg > 0 && deg <= 64) {
        // ---- single-pass softmax in registers ----
        int j = lo + lane;
        bool act = j < hi;
        int t = act ? edge_t[j] : 0;
        float e = act ? si + sdst[t] : -INFINITY;
        e = (e > 0.f) ? e : 0.2f * e;
        float m = e;
#pragma unroll
        for (int off = 32; off; off >>= 1) m = fmaxf(m, __shfl_xor(m, off));
        float p = act ? __expf(e - m) : 0.f;
        float den = p;
#pragma unroll
        for (int off = 32; off; off >>= 1) den += __shfl_xor(den, off);
        float w = p / den;   // inactive lanes: 0

        const u16* xj = xbf + (size_t)j16 * 8;   // chunk base (elements)

        if (deg <= 32) {
            // ---- 8 guarded batches of 4 edges, paired loads ----
#pragma unroll
            for (int bb = 0; bb < 4; ++bb) {
                if (deg > bb * 8) {
                    int e0 = bb * 8 + eg;
                    int e1 = bb * 8 + 4 + eg;
                    int  t0 = __shfl(t, e0); float w0 = __shfl(w, e0);
                    u16x8 v0 = *(const u16x8*)(xj + (size_t)t0 * OUT_DIM);
                    bool has1 = deg > bb * 8 + 4;
                    int t1 = 0; float w1 = 0.f; u16x8 v1;
                    if (has1) {
                        t1 = __shfl(t, e1); w1 = __shfl(w, e1);
                        v1 = *(const u16x8*)(xj + (size_t)t1 * OUT_DIM);
                    }
#pragma unroll
                    for (int d = 0; d < 8; d++) acc[d] += w0 * bf2f(v0[d]);
                    if (has1) {
#pragma unroll
                        for (int d = 0; d < 8; d++) acc[d] += w1 * bf2f(v1[d]);
                    }
                }
            }
        } else {
            // deg in (32,64]: guarded 4-edge batch loop
            int nit = (deg + 3) >> 2;
            for (int it = 0; it < nit; ++it) {
                int ei = it * 4 + eg;
                int tt = __shfl(t, ei);
                float ww = __shfl(w, ei);
                if (ei < deg) {
                    u16x8 v = *(const u16x8*)(xj + (size_t)tt * OUT_DIM);
#pragma unroll
                    for (int d = 0; d < 8; d++) acc[d] += ww * bf2f(v[d]);
                }
            }
        }
    } else if (deg > 64) {
        // ---- general path: strided passes ----
        float m = -INFINITY;
        for (int j = lo + lane; j < hi; j += 64) {
            int t = edge_t[j];
            float e = si + sdst[t];
            e = (e > 0.f) ? e : 0.2f * e;
            m = fmaxf(m, e);
        }
#pragma unroll
        for (int off = 32; off; off >>= 1) m = fmaxf(m, __shfl_xor(m, off));
        float den = 0.f;
        for (int j = lo + lane; j < hi; j += 64) {
            int t = edge_t[j];
            float e = si + sdst[t];
            e = (e > 0.f) ? e : 0.2f * e;
            den += __expf(e - m);
        }
#pragma unroll
        for (int off = 32; off; off >>= 1) den += __shfl_xor(den, off);
        const float invden = 1.f / den;

        const u16* xj = xbf + (size_t)j16 * 8;
        for (int jj = lo; jj < hi; jj += 4) {
            int ei = jj + eg;
            if (ei < hi) {
                int tt = edge_t[ei];
                float e = si + sdst[tt];
                e = (e > 0.f) ? e : 0.2f * e;
                float ww = __expf(e - m) * invden;
                u16x8 v = *(const u16x8*)(xj + (size_t)tt * OUT_DIM);
#pragma unroll
                for (int d = 0; d < 8; d++) acc[d] += ww * bf2f(v[d]);
            }
        }
    }

    // ---- cross-group reduce over eg (lane bits 4-5) ----
#pragma unroll
    for (int d = 0; d < 8; d++) acc[d] += __shfl_xor(acc[d], 16);
#pragma unroll
    for (int d = 0; d < 8; d++) acc[d] += __shfl_xor(acc[d], 32);

    // ---- epilogue from 16 lanes (eg==0): elu(acc + x_i), dims [j16*8, +8) ----
    if (lane < 16) {
        u16x8 xi = *(const u16x8*)(xbf + (size_t)i * OUT_DIM + j16 * 8);
        float o[8];
#pragma unroll
        for (int d = 0; d < 8; d++) {
            float v = acc[d] + bf2f(xi[d]);
            o[d] = (v > 0.f) ? v : __expf(v) - 1.f;
        }
        float* dst = out + (size_t)i * OUT_DIM + j16 * 8;
        *(float4*)(dst)     = make_float4(o[0], o[1], o[2], o[3]);
        *(float4*)(dst + 4) = make_float4(o[4], o[5], o[6], o[7]);
    }
}

// ---------------------------------------------------------------------------
extern "C" void kernel_launch(void* const* d_in, const int* in_sizes, int n_in,
                              void* d_out, int out_size, void* d_ws, size_t ws_size,
                              hipStream_t stream)
{
    const float* input  = (const float*)d_in[0];
    const float* W      = (const float*)d_in[1];
    const float* a      = (const float*)d_in[2];
    const int*   triple = (const int*)d_in[3];
    const int N = in_sizes[0] / IN_DIM;
    const int E = in_sizes[3] / 3;
    float* out = (float*)d_out;

    const int NBC = (N + BNODES - 1) >> BSHIFT;   // coarse buckets (<=256)

    // workspace layout
    char* p = (char*)d_ws;
    auto carve = [&](size_t bytes) {
        char* q = p;
        p += (bytes + 15) & ~(size_t)15;
        return q;
    };
    u16*  xbf       = (u16*)carve((size_t)N * OUT_DIM * sizeof(u16));
    u16*  Wt        = (u16*)carve((size_t)IN_DIM * OUT_DIM * sizeof(u16));
    float* ssrc     = (float*)carve((size_t)N * sizeof(float));
    float* sdst     = (float*)carve((size_t)N * sizeof(float));
    int*  startp    = (int*)carve((size_t)(N + 1) * sizeof(int));
    int*  coarse_cur= (int*)carve(256 * sizeof(int));
    int*  edge_t    = (int*)carve((size_t)E * sizeof(int));
    uint2* pairs    = (uint2*)carve((size_t)NBC * CAP * sizeof(uint2));

    const int nScat = (E + 256 * EPT - 1) / (256 * EPT);
    const int nGemm = (N + BM - 1) / BM;

    hipMemsetAsync(coarse_cur, 0, 256 * sizeof(int), stream);
    wt_kernel<<<IN_DIM, OUT_DIM, 0, stream>>>(W, Wt);
    gemm_scatter_kernel<<<nScat + nGemm, 256, 0, stream>>>(
        input, Wt, a, xbf, ssrc, sdst, triple, coarse_cur, pairs, N, E, NBC, nScat);
    bucket_csr_kernel<<<NBC, BNODES, 0, stream>>>(pairs, coarse_cur, startp, edge_t, N, E, NBC);
    aggregate_kernel<<<(N + 3) / 4, 256, 0, stream>>>(xbf, ssrc, sdst, startp, edge_t, out, N);
}

// Round 11
// 137.819 us; speedup vs baseline: 3.0673x; 1.0213x over previous
//
#include <hip/hip_runtime.h>
#include <hip/hip_bf16.h>
#include <math.h>

#define IN_DIM 128
#define OUT_DIM 128
#define BM 64

#define BSHIFT 9            // nodes per coarse bucket = 512
#define BNODES 512
#define CAP 12288           // pair capacity per coarse bucket region
#define EPT 16              // edges per thread in coarse_scatter

typedef short bf16x8s __attribute__((ext_vector_type(8)));
typedef float f32x4 __attribute__((ext_vector_type(4)));
typedef unsigned short u16;
typedef unsigned short u16x8 __attribute__((ext_vector_type(8)));

__device__ inline unsigned int rne_hi(float f) {
    unsigned int u = __float_as_uint(f);
    return u + 0x7fffu + ((u >> 16) & 1u);   // high 16 bits = RNE bf16
}
__device__ inline unsigned int pack_bf16x2(float lo, float hi) {
    return (rne_hi(lo) >> 16) | (rne_hi(hi) & 0xffff0000u);
}
__device__ inline float bf2f(u16 v) { return __uint_as_float(((unsigned)v) << 16); }

// ---------------------------------------------------------------------------
// K0: transpose + convert W [k][c] fp32 -> Wt bf16 [c][k]
// ---------------------------------------------------------------------------
__global__ void wt_kernel(const float* __restrict__ W, u16* __restrict__ Wt)
{
    int k = blockIdx.x;
    int c = threadIdx.x;
    Wt[c * IN_DIM + k] = (u16)(rne_hi(W[k * OUT_DIM + c]) >> 16);
}

// ---------------------------------------------------------------------------
// K1: FUSED gemm + coarse_scatter (proven round-10 version).
// ---------------------------------------------------------------------------
__global__ __launch_bounds__(256) void gemm_scatter_kernel(
    const float* __restrict__ in, const u16* __restrict__ WtG,
    const float* __restrict__ a, u16* __restrict__ xbf,
    float* __restrict__ ssrc, float* __restrict__ sdst,
    const int* __restrict__ triple, int* __restrict__ coarse_cur,
    uint2* __restrict__ pairs, int N, int E, int nbc, int nScat)
{
    const int tid = threadIdx.x;

    if ((int)blockIdx.x < nScat) {
        __shared__ int cnt[256];
        __shared__ int base[256];
        const int cbase = blockIdx.x * (256 * EPT);

        cnt[tid] = 0;
        __syncthreads();

        int h[EPT], t[EPT], pos[EPT];
#pragma unroll
        for (int it = 0; it < EPT; ++it) {
            int idx = cbase + it * 256 + tid;
            if (idx < E) {
                h[it] = triple[3 * idx];
                t[it] = triple[3 * idx + 2];
                pos[it] = atomicAdd(&cnt[h[it] >> BSHIFT], 1);
            }
        }
        __syncthreads();
        if (tid < nbc && cnt[tid] > 0)
            base[tid] = tid * CAP + atomicAdd(&coarse_cur[tid], cnt[tid]);
        __syncthreads();
#pragma unroll
        for (int it = 0; it < EPT; ++it) {
            int idx = cbase + it * 256 + tid;
            if (idx < E)
                pairs[base[h[it] >> BSHIFT] + pos[it]] =
                    make_uint2((unsigned)h[it], (unsigned)t[it]);
        }
        return;
    }

    __shared__ u16 Al[BM][IN_DIM + 8];
    __shared__ u16 Wl[OUT_DIM][IN_DIM + 8];

    const int gb   = blockIdx.x - nScat;
    const int lane = tid & 63;
    const int wave = tid >> 6;
    const int rl   = lane & 15;
    const int rgrp = lane >> 4;

    {
        int r = tid >> 1, c0 = (tid & 1) * 64;
        const uint4* src = (const uint4*)(WtG + r * IN_DIM + c0);
        uint4* dst = (uint4*)&Wl[r][c0];
#pragma unroll
        for (int u = 0; u < 8; u++) dst[u] = src[u];
    }
    const long long rowbase = (long long)gb * BM;
    {
#pragma unroll
        for (int u = 0; u < 8; u++) {
            int idx = u * 256 + tid;
            int r = idx >> 5;
            int c = (idx & 31) * 4;
            long long gr = rowbase + r;
            if (gr >= N) gr = N - 1;
            float4 v = *(const float4*)(in + gr * IN_DIM + c);
            *(uint2*)&Al[r][c] = make_uint2(pack_bf16x2(v.x, v.y), pack_bf16x2(v.z, v.w));
        }
    }
    __syncthreads();

    f32x4 acc[8] = {};
#pragma unroll
    for (int ks = 0; ks < 4; ks++) {
        bf16x8s af = *(const bf16x8s*)&Al[wave * 16 + rl][ks * 32 + rgrp * 8];
#pragma unroll
        for (int cb = 0; cb < 8; cb++) {
            bf16x8s bf = *(const bf16x8s*)&Wl[cb * 16 + rl][ks * 32 + rgrp * 8];
            acc[cb] = __builtin_amdgcn_mfma_f32_16x16x32_bf16(af, bf, acc[cb], 0, 0, 0);
        }
    }

    float a_sv[8], a_dv[8];
#pragma unroll
    for (int cb = 0; cb < 8; cb++) {
        a_sv[cb] = a[rl + 16 * cb];
        a_dv[cb] = a[OUT_DIM + rl + 16 * cb];
    }
#pragma unroll
    for (int r = 0; r < 4; r++) {
        long long grow = rowbase + wave * 16 + rgrp * 4 + r;
        float ps = 0.f, pd = 0.f;
#pragma unroll
        for (int cb = 0; cb < 8; cb++) {
            float v = acc[cb][r];
            if (grow < N) xbf[grow * OUT_DIM + rl + 16 * cb] = (u16)(rne_hi(v) >> 16);
            ps += v * a_sv[cb];
            pd += v * a_dv[cb];
        }
#pragma unroll
        for (int off = 1; off < 16; off <<= 1) {
            ps += __shfl_xor(ps, off);
            pd += __shfl_xor(pd, off);
        }
        if (rl == 0 && grow < N) { ssrc[grow] = ps; sdst[grow] = pd; }
    }
}

// ---------------------------------------------------------------------------
// K2: per-bucket CSR build with inline bucket-size scan (round-10 version).
// ---------------------------------------------------------------------------
__global__ __launch_bounds__(512) void bucket_csr_kernel(
    const uint2* __restrict__ pairs, const int* __restrict__ coarse_cur,
    int* __restrict__ startp, int* __restrict__ edge_t, int N, int E, int nbc)
{
    __shared__ int cnt[BNODES];
    __shared__ int scn[BNODES];
    __shared__ int cursor[BNODES];
    __shared__ int bsum[256];
    const int b = blockIdx.x;
    const int tid = threadIdx.x;
    const int plo = b * CAP;
    const int psz = coarse_cur[b];

    if (tid < 256) bsum[tid] = (tid < nbc) ? coarse_cur[tid] : 0;
    __syncthreads();
#pragma unroll
    for (int off = 1; off < 256; off <<= 1) {
        int v = 0;
        if (tid < 256 && tid >= off) v = bsum[tid - off];
        __syncthreads();
        if (tid < 256 && tid >= off) bsum[tid] += v;
        __syncthreads();
    }
    const int obase = bsum[b] - psz;

    cnt[tid] = 0;
    __syncthreads();
    for (int j = tid; j < psz; j += BNODES)
        atomicAdd(&cnt[pairs[plo + j].x & (BNODES - 1)], 1);
    __syncthreads();
    scn[tid] = cnt[tid];
    __syncthreads();
#pragma unroll
    for (int off = 1; off < BNODES; off <<= 1) {
        int v = (tid >= off) ? scn[tid - off] : 0;
        __syncthreads();
        scn[tid] += v;
        __syncthreads();
    }
    const int excl = scn[tid] - cnt[tid];
    const int node = b * BNODES + tid;
    if (node < N) startp[node] = obase + excl;
    cursor[tid] = obase + excl;
    __syncthreads();
    for (int j = tid; j < psz; j += BNODES) {
        uint2 p = pairs[plo + j];
        int pos = atomicAdd(&cursor[p.x & (BNODES - 1)], 1);
        edge_t[pos] = (int)p.y;
    }
    if (b == 0 && tid == 0) startp[N] = E;
}

// ---------------------------------------------------------------------------
// K3: per-node softmax aggregation, TWO nodes per wave.
// Lanes 0-31 = node A, 32-63 = node B: each half runs a 32-lane in-register
// softmax. Gather: 4 edge-slots x 16 lanes (2 slots per node) — one load
// instruction per edge, 16B/lane contiguous (4 line-touches per 256B row).
// Slow paths (deg>32) fall back to full-wave processing per node (rare).
// ---------------------------------------------------------------------------
__global__ __launch_bounds__(256) void aggregate_kernel(
    const u16* __restrict__ xbf, const float* __restrict__ ssrc,
    const float* __restrict__ sdst, const int* __restrict__ startp,
    const int* __restrict__ edge_t, float* __restrict__ out, int N)
{
    const int wid  = threadIdx.x >> 6;
    const int lane = threadIdx.x & 63;
    const int i0 = (blockIdx.x * 4 + wid) * 2;    // wave's first node
    if (i0 >= N) return;
    const int half = lane >> 5;                   // 0 = node A, 1 = node B
    const int l32  = lane & 31;
    const int iH   = i0 + half;
    const bool hasH = iH < N;
    const int j16 = lane & 15;                    // 16B chunk 0..15

    int lo = 0, hi = 0;
    if (hasH) { lo = startp[iH]; hi = startp[iH + 1]; }
    const int deg = hi - lo;
    const int degO = __shfl_xor(deg, 32);
    const int degMax = max(deg, degO);

    float acc[8];
#pragma unroll
    for (int d = 0; d < 8; d++) acc[d] = 0.f;

    if (degMax <= 32) {
        // ---- per-half 32-lane softmax ----
        const float si = hasH ? ssrc[iH] : 0.f;
        bool act = l32 < deg;
        int t = act ? edge_t[lo + l32] : 0;
        float e = act ? si + sdst[t] : -INFINITY;
        e = (e > 0.f) ? e : 0.2f * e;
        float m = e;
#pragma unroll
        for (int off = 16; off; off >>= 1) m = fmaxf(m, __shfl_xor(m, off));
        float p = act ? __expf(e - m) : 0.f;
        float den = p;
#pragma unroll
        for (int off = 16; off; off >>= 1) den += __shfl_xor(den, off);
        float w = (deg > 0) ? p / den : 0.f;      // inactive lanes: 0

        // ---- gather: 4 slots = 2 per node; slots beyond a node's deg have
        // w=0 from the source lane (t=0 row is L1-hot, contribution 0) ----
        const int slot = (lane >> 4) & 1;         // slot within node
        const int srcBase = (lane >> 5) << 5;     // 0 for A-lanes, 32 for B
        const u16* xj = xbf + (size_t)j16 * 8;

        for (int bb = 0; bb * 2 < degMax; ++bb) {
            int ei = bb * 2 + slot;
            int tt = __shfl(t, srcBase + ei);
            float ww = __shfl(w, srcBase + ei);
            u16x8 v = *(const u16x8*)(xj + (size_t)tt * OUT_DIM);
#pragma unroll
            for (int d = 0; d < 8; d++) acc[d] += ww * bf2f(v[d]);
        }

        // reduce the two slots of each node (lane bit 4)
#pragma unroll
        for (int d = 0; d < 8; d++) acc[d] += __shfl_xor(acc[d], 16);

        if (!(lane & 16) && hasH) {
            u16x8 xi = *(const u16x8*)(xbf + (size_t)iH * OUT_DIM + j16 * 8);
            float o[8];
#pragma unroll
            for (int d = 0; d < 8; d++) {
                float v = acc[d] + bf2f(xi[d]);
                o[d] = (v > 0.f) ? v : __expf(v) - 1.f;
            }
            float* dst = out + (size_t)iH * OUT_DIM + j16 * 8;
            *(float4*)(dst)     = make_float4(o[0], o[1], o[2], o[3]);
            *(float4*)(dst + 4) = make_float4(o[4], o[5], o[6], o[7]);
        }
        return;
    }

    // ================= rare slow path: full wave per node =================
    const int eg = lane >> 4;   // edge slot 0..3
    for (int h = 0; h < 2; ++h) {
        const int i = i0 + h;
        if (i >= N) break;
        const int slo = startp[i];
        const int shi = startp[i + 1];
        const int sdeg = shi - slo;
        const float si = ssrc[i];

#pragma unroll
        for (int d = 0; d < 8; d++) acc[d] = 0.f;

        if (sdeg > 0 && sdeg <= 64) {
            int j = slo + lane;
            bool act = j < shi;
            int t = act ? edge_t[j] : 0;
            float e = act ? si + sdst[t] : -INFINITY;
            e = (e > 0.f) ? e : 0.2f * e;
            float m = e;
#pragma unroll
            for (int off = 32; off; off >>= 1) m = fmaxf(m, __shfl_xor(m, off));
            float p = act ? __expf(e - m) : 0.f;
            float den = p;
#pragma unroll
            for (int off = 32; off; off >>= 1) den += __shfl_xor(den, off);
            float w = p / den;

            const u16* xj = xbf + (size_t)j16 * 8;
            int nit = (sdeg + 3) >> 2;
            for (int it = 0; it < nit; ++it) {
                int ei = it * 4 + eg;
                int tt = __shfl(t, ei);
                float ww = __shfl(w, ei);
                if (ei < sdeg) {
                    u16x8 v = *(const u16x8*)(xj + (size_t)tt * OUT_DIM);
#pragma unroll
                    for (int d = 0; d < 8; d++) acc[d] += ww * bf2f(v[d]);
                }
            }
        } else if (sdeg > 64) {
            float m = -INFINITY;
            for (int j = slo + lane; j < shi; j += 64) {
                int t = edge_t[j];
                float e = si + sdst[t];
                e = (e > 0.f) ? e : 0.2f * e;
                m = fmaxf(m, e);
            }
#pragma unroll
            for (int off = 32; off; off >>= 1) m = fmaxf(m, __shfl_xor(m, off));
            float den = 0.f;
            for (int j = slo + lane; j < shi; j += 64) {
                int t = edge_t[j];
                float e = si + sdst[t];
                e = (e > 0.f) ? e : 0.2f * e;
                den += __expf(e - m);
            }
#pragma unroll
            for (int off = 32; off; off >>= 1) den += __shfl_xor(den, off);
            const float invden = 1.f / den;

            const u16* xj = xbf + (size_t)j16 * 8;
            for (int jj = slo; jj < shi; jj += 4) {
                int ei = jj + eg;
                if (ei < shi) {
                    int tt = edge_t[ei];
                    float e = si + sdst[tt];
                    e = (e > 0.f) ? e : 0.2f * e;
                    float ww = __expf(e - m) * invden;
                    u16x8 v = *(const u16x8*)(xj + (size_t)tt * OUT_DIM);
#pragma unroll
                    for (int d = 0; d < 8; d++) acc[d] += ww * bf2f(v[d]);
                }
            }
        }

#pragma unroll
        for (int d = 0; d < 8; d++) acc[d] += __shfl_xor(acc[d], 16);
#pragma unroll
        for (int d = 0; d < 8; d++) acc[d] += __shfl_xor(acc[d], 32);

        if (lane < 16) {
            u16x8 xi = *(const u16x8*)(xbf + (size_t)i * OUT_DIM + j16 * 8);
            float o[8];
#pragma unroll
            for (int d = 0; d < 8; d++) {
                float v = acc[d] + bf2f(xi[d]);
                o[d] = (v > 0.f) ? v : __expf(v) - 1.f;
            }
            float* dst = out + (size_t)i * OUT_DIM + j16 * 8;
            *(float4*)(dst)     = make_float4(o[0], o[1], o[2], o[3]);
            *(float4*)(dst + 4) = make_float4(o[4], o[5], o[6], o[7]);
        }
    }
}

// ---------------------------------------------------------------------------
extern "C" void kernel_launch(void* const* d_in, const int* in_sizes, int n_in,
                              void* d_out, int out_size, void* d_ws, size_t ws_size,
                              hipStream_t stream)
{
    const float* input  = (const float*)d_in[0];
    const float* W      = (const float*)d_in[1];
    const float* a      = (const float*)d_in[2];
    const int*   triple = (const int*)d_in[3];
    const int N = in_sizes[0] / IN_DIM;
    const int E = in_sizes[3] / 3;
    float* out = (float*)d_out;

    const int NBC = (N + BNODES - 1) >> BSHIFT;   // coarse buckets (<=256)

    // workspace layout
    char* p = (char*)d_ws;
    auto carve = [&](size_t bytes) {
        char* q = p;
        p += (bytes + 15) & ~(size_t)15;
        return q;
    };
    u16*  xbf       = (u16*)carve((size_t)N * OUT_DIM * sizeof(u16));
    u16*  Wt        = (u16*)carve((size_t)IN_DIM * OUT_DIM * sizeof(u16));
    float* ssrc     = (float*)carve((size_t)N * sizeof(float));
    float* sdst     = (float*)carve((size_t)N * sizeof(float));
    int*  startp    = (int*)carve((size_t)(N + 1) * sizeof(int));
    int*  coarse_cur= (int*)carve(256 * sizeof(int));
    int*  edge_t    = (int*)carve((size_t)E * sizeof(int));
    uint2* pairs    = (uint2*)carve((size_t)NBC * CAP * sizeof(uint2));

    const int nScat = (E + 256 * EPT - 1) / (256 * EPT);
    const int nGemm = (N + BM - 1) / BM;

    hipMemsetAsync(coarse_cur, 0, 256 * sizeof(int), stream);
    wt_kernel<<<IN_DIM, OUT_DIM, 0, stream>>>(W, Wt);
    gemm_scatter_kernel<<<nScat + nGemm, 256, 0, stream>>>(
        input, Wt, a, xbf, ssrc, sdst, triple, coarse_cur, pairs, N, E, NBC, nScat);
    bucket_csr_kernel<<<NBC, BNODES, 0, stream>>>(pairs, coarse_cur, startp, edge_t, N, E, NBC);
    aggregate_kernel<<<(N + 7) / 8, 256, 0, stream>>>(xbf, ssrc, sdst, startp, edge_t, out, N);
}

// Round 12
// 126.541 us; speedup vs baseline: 3.3407x; 1.0891x over previous
//
#include <hip/hip_runtime.h>
#include <hip/hip_bf16.h>
#include <math.h>

#define IN_DIM 128
#define OUT_DIM 128
#define BM 64

#define BSHIFT 9            // nodes per coarse bucket = 512
#define BNODES 512
#define CAP 12288           // pair capacity per coarse bucket region
#define EPT 16              // edges per thread in coarse_scatter

typedef short bf16x8s __attribute__((ext_vector_type(8)));
typedef float f32x4 __attribute__((ext_vector_type(4)));
typedef unsigned short u16;
typedef unsigned char u8;

__device__ inline unsigned int rne_hi(float f) {
    unsigned int u = __float_as_uint(f);
    return u + 0x7fffu + ((u >> 16) & 1u);   // high 16 bits = RNE bf16
}
__device__ inline unsigned int pack_bf16x2(float lo, float hi) {
    return (rne_hi(lo) >> 16) | (rne_hi(hi) & 0xffff0000u);
}
__device__ inline float byf(unsigned int u, int sh) {
    return (float)((u >> sh) & 0xffu);       // -> v_cvt_f32_ubyteN
}

// ---------------------------------------------------------------------------
// K0: transpose + convert W [k][c] fp32 -> Wt bf16 [c][k]
// ---------------------------------------------------------------------------
__global__ void wt_kernel(const float* __restrict__ W, u16* __restrict__ Wt)
{
    int k = blockIdx.x;
    int c = threadIdx.x;
    Wt[c * IN_DIM + k] = (u16)(rne_hi(W[k * OUT_DIM + c]) >> 16);
}

// ---------------------------------------------------------------------------
// K1: FUSED gemm + coarse_scatter. Gemm epilogue now row-quantizes x to
// int8 (biased by 128) with per-row scale ssx = rowmax/127.
// ---------------------------------------------------------------------------
__global__ __launch_bounds__(256) void gemm_scatter_kernel(
    const float* __restrict__ in, const u16* __restrict__ WtG,
    const float* __restrict__ a, u8* __restrict__ xq, float* __restrict__ ssx,
    float* __restrict__ ssrc, float* __restrict__ sdst,
    const int* __restrict__ triple, int* __restrict__ coarse_cur,
    uint2* __restrict__ pairs, int N, int E, int nbc, int nScat)
{
    const int tid = threadIdx.x;

    if ((int)blockIdx.x < nScat) {
        __shared__ int cnt[256];
        __shared__ int base[256];
        const int cbase = blockIdx.x * (256 * EPT);

        cnt[tid] = 0;
        __syncthreads();

        int h[EPT], t[EPT], pos[EPT];
#pragma unroll
        for (int it = 0; it < EPT; ++it) {
            int idx = cbase + it * 256 + tid;
            if (idx < E) {
                h[it] = triple[3 * idx];
                t[it] = triple[3 * idx + 2];
                pos[it] = atomicAdd(&cnt[h[it] >> BSHIFT], 1);
            }
        }
        __syncthreads();
        if (tid < nbc && cnt[tid] > 0)
            base[tid] = tid * CAP + atomicAdd(&coarse_cur[tid], cnt[tid]);
        __syncthreads();
#pragma unroll
        for (int it = 0; it < EPT; ++it) {
            int idx = cbase + it * 256 + tid;
            if (idx < E)
                pairs[base[h[it] >> BSHIFT] + pos[it]] =
                    make_uint2((unsigned)h[it], (unsigned)t[it]);
        }
        return;
    }

    __shared__ u16 Al[BM][IN_DIM + 8];
    __shared__ u16 Wl[OUT_DIM][IN_DIM + 8];

    const int gb   = blockIdx.x - nScat;
    const int lane = tid & 63;
    const int wave = tid >> 6;
    const int rl   = lane & 15;
    const int rgrp = lane >> 4;

    {
        int r = tid >> 1, c0 = (tid & 1) * 64;
        const uint4* src = (const uint4*)(WtG + r * IN_DIM + c0);
        uint4* dst = (uint4*)&Wl[r][c0];
#pragma unroll
        for (int u = 0; u < 8; u++) dst[u] = src[u];
    }
    const long long rowbase = (long long)gb * BM;
    {
#pragma unroll
        for (int u = 0; u < 8; u++) {
            int idx = u * 256 + tid;
            int r = idx >> 5;
            int c = (idx & 31) * 4;
            long long gr = rowbase + r;
            if (gr >= N) gr = N - 1;
            float4 v = *(const float4*)(in + gr * IN_DIM + c);
            *(uint2*)&Al[r][c] = make_uint2(pack_bf16x2(v.x, v.y), pack_bf16x2(v.z, v.w));
        }
    }
    __syncthreads();

    f32x4 acc[8] = {};
#pragma unroll
    for (int ks = 0; ks < 4; ks++) {
        bf16x8s af = *(const bf16x8s*)&Al[wave * 16 + rl][ks * 32 + rgrp * 8];
#pragma unroll
        for (int cb = 0; cb < 8; cb++) {
            bf16x8s bf = *(const bf16x8s*)&Wl[cb * 16 + rl][ks * 32 + rgrp * 8];
            acc[cb] = __builtin_amdgcn_mfma_f32_16x16x32_bf16(af, bf, acc[cb], 0, 0, 0);
        }
    }

    float a_sv[8], a_dv[8];
#pragma unroll
    for (int cb = 0; cb < 8; cb++) {
        a_sv[cb] = a[rl + 16 * cb];
        a_dv[cb] = a[OUT_DIM + rl + 16 * cb];
    }
#pragma unroll
    for (int r = 0; r < 4; r++) {
        long long grow = rowbase + wave * 16 + rgrp * 4 + r;
        float ps = 0.f, pd = 0.f, rm = 0.f;
#pragma unroll
        for (int cb = 0; cb < 8; cb++) {
            float v = acc[cb][r];
            ps += v * a_sv[cb];
            pd += v * a_dv[cb];
            rm = fmaxf(rm, fabsf(v));
        }
#pragma unroll
        for (int off = 1; off < 16; off <<= 1) {
            ps += __shfl_xor(ps, off);
            pd += __shfl_xor(pd, off);
            rm = fmaxf(rm, __shfl_xor(rm, off));
        }
        rm = fmaxf(rm, 1e-20f);
        const float inv = 127.0f / rm;
        if (grow < N) {
#pragma unroll
            for (int cb = 0; cb < 8; cb++)
                xq[grow * OUT_DIM + rl + 16 * cb] =
                    (u8)(int)(fmaf(acc[cb][r], inv, 128.5f));
            if (rl == 0) {
                ssrc[grow] = ps;
                sdst[grow] = pd;
                ssx[grow]  = rm * (1.0f / 127.0f);
            }
        }
    }
}

// ---------------------------------------------------------------------------
// K2: per-bucket CSR build with inline bucket-size scan (round-10 version).
// ---------------------------------------------------------------------------
__global__ __launch_bounds__(512) void bucket_csr_kernel(
    const uint2* __restrict__ pairs, const int* __restrict__ coarse_cur,
    int* __restrict__ startp, int* __restrict__ edge_t, int N, int E, int nbc)
{
    __shared__ int cnt[BNODES];
    __shared__ int scn[BNODES];
    __shared__ int cursor[BNODES];
    __shared__ int bsum[256];
    const int b = blockIdx.x;
    const int tid = threadIdx.x;
    const int plo = b * CAP;
    const int psz = coarse_cur[b];

    if (tid < 256) bsum[tid] = (tid < nbc) ? coarse_cur[tid] : 0;
    __syncthreads();
#pragma unroll
    for (int off = 1; off < 256; off <<= 1) {
        int v = 0;
        if (tid < 256 && tid >= off) v = bsum[tid - off];
        __syncthreads();
        if (tid < 256 && tid >= off) bsum[tid] += v;
        __syncthreads();
    }
    const int obase = bsum[b] - psz;

    cnt[tid] = 0;
    __syncthreads();
    for (int j = tid; j < psz; j += BNODES)
        atomicAdd(&cnt[pairs[plo + j].x & (BNODES - 1)], 1);
    __syncthreads();
    scn[tid] = cnt[tid];
    __syncthreads();
#pragma unroll
    for (int off = 1; off < BNODES; off <<= 1) {
        int v = (tid >= off) ? scn[tid - off] : 0;
        __syncthreads();
        scn[tid] += v;
        __syncthreads();
    }
    const int excl = scn[tid] - cnt[tid];
    const int node = b * BNODES + tid;
    if (node < N) startp[node] = obase + excl;
    cursor[tid] = obase + excl;
    __syncthreads();
    for (int j = tid; j < psz; j += BNODES) {
        uint2 p = pairs[plo + j];
        int pos = atomicAdd(&cursor[p.x & (BNODES - 1)], 1);
        edge_t[pos] = (int)p.y;
    }
    if (b == 0 && tid == 0) startp[N] = E;
}

// ---------------------------------------------------------------------------
// K3: aggregation, TWO nodes per wave, int8 row-quantized gather table.
// agg_d = Sigma cs_j*q_jd - S128, cs = w*ssx[t], S128 = 128*Sigma cs.
// Residual also from int8: + ssx[i]*(q_i - 128). 128B rows: 2 line-touches.
// ---------------------------------------------------------------------------
__global__ __launch_bounds__(256) void aggregate_kernel(
    const u8* __restrict__ xq, const float* __restrict__ ssx,
    const float* __restrict__ ssrc, const float* __restrict__ sdst,
    const int* __restrict__ startp, const int* __restrict__ edge_t,
    float* __restrict__ out, int N)
{
    const int wid  = threadIdx.x >> 6;
    const int lane = threadIdx.x & 63;
    const int i0 = (blockIdx.x * 4 + wid) * 2;
    if (i0 >= N) return;
    const int half = lane >> 5;
    const int l32  = lane & 31;
    const int iH   = i0 + half;
    const bool hasH = iH < N;
    const int j16 = lane & 15;

    int lo = 0, hi = 0;
    if (hasH) { lo = startp[iH]; hi = startp[iH + 1]; }
    const int deg = hi - lo;
    const int degO = __shfl_xor(deg, 32);
    const int degMax = max(deg, degO);

    float acc[8];
#pragma unroll
    for (int d = 0; d < 8; d++) acc[d] = 0.f;

    if (degMax <= 32) {
        const float si = hasH ? ssrc[iH] : 0.f;
        bool act = l32 < deg;
        int t = act ? edge_t[lo + l32] : 0;
        float sde = act ? sdst[t] : 0.f;
        float ssl = act ? ssx[t] : 0.f;
        float e = act ? si + sde : -INFINITY;
        e = (e > 0.f) ? e : 0.2f * e;
        float m = e;
#pragma unroll
        for (int off = 16; off; off >>= 1) m = fmaxf(m, __shfl_xor(m, off));
        float p = act ? __expf(e - m) : 0.f;
        float den = p;
#pragma unroll
        for (int off = 16; off; off >>= 1) den += __shfl_xor(den, off);
        float w = (deg > 0) ? p / den : 0.f;
        float cs = w * ssl;
        float Ss = cs;
#pragma unroll
        for (int off = 16; off; off >>= 1) Ss += __shfl_xor(Ss, off);

        const int slot = (lane >> 4) & 1;
        const int srcBase = half << 5;
        const u8* xj = xq + j16 * 8;

        for (int bb = 0; bb * 2 < degMax; ++bb) {
            int ei = bb * 2 + slot;
            int tt = __shfl(t, srcBase + ei);
            float cc = __shfl(cs, srcBase + ei);
            uint2 v = *(const uint2*)(xj + (size_t)tt * OUT_DIM);
            acc[0] += cc * byf(v.x, 0);
            acc[1] += cc * byf(v.x, 8);
            acc[2] += cc * byf(v.x, 16);
            acc[3] += cc * byf(v.x, 24);
            acc[4] += cc * byf(v.y, 0);
            acc[5] += cc * byf(v.y, 8);
            acc[6] += cc * byf(v.y, 16);
            acc[7] += cc * byf(v.y, 24);
        }

#pragma unroll
        for (int d = 0; d < 8; d++) acc[d] += __shfl_xor(acc[d], 16);

        if (!(lane & 16) && hasH) {
            float ssi = ssx[iH];
            float r0 = -128.f * Ss - 128.f * ssi;
            uint2 rv = *(const uint2*)(xq + (size_t)iH * OUT_DIM + j16 * 8);
            float o[8];
            o[0] = fmaf(ssi, byf(rv.x, 0),  acc[0] + r0);
            o[1] = fmaf(ssi, byf(rv.x, 8),  acc[1] + r0);
            o[2] = fmaf(ssi, byf(rv.x, 16), acc[2] + r0);
            o[3] = fmaf(ssi, byf(rv.x, 24), acc[3] + r0);
            o[4] = fmaf(ssi, byf(rv.y, 0),  acc[4] + r0);
            o[5] = fmaf(ssi, byf(rv.y, 8),  acc[5] + r0);
            o[6] = fmaf(ssi, byf(rv.y, 16), acc[6] + r0);
            o[7] = fmaf(ssi, byf(rv.y, 24), acc[7] + r0);
#pragma unroll
            for (int d = 0; d < 8; d++)
                o[d] = (o[d] > 0.f) ? o[d] : __expf(o[d]) - 1.f;
            float* dst = out + (size_t)iH * OUT_DIM + j16 * 8;
            *(float4*)(dst)     = make_float4(o[0], o[1], o[2], o[3]);
            *(float4*)(dst + 4) = make_float4(o[4], o[5], o[6], o[7]);
        }
        return;
    }

    // ================= rare slow path: full wave per node =================
    const int eg = lane >> 4;
    for (int h = 0; h < 2; ++h) {
        const int i = i0 + h;
        if (i >= N) break;
        const int slo = startp[i];
        const int shi = startp[i + 1];
        const int sdeg = shi - slo;
        const float si = ssrc[i];
        float S128 = 0.f;

#pragma unroll
        for (int d = 0; d < 8; d++) acc[d] = 0.f;
        const u8* xj = xq + j16 * 8;

        if (sdeg > 0 && sdeg <= 64) {
            int j = slo + lane;
            bool act = j < shi;
            int t = act ? edge_t[j] : 0;
            float ssl = act ? ssx[t] : 0.f;
            float e = act ? si + sdst[t] : -INFINITY;
            e = (e > 0.f) ? e : 0.2f * e;
            float m = e;
#pragma unroll
            for (int off = 32; off; off >>= 1) m = fmaxf(m, __shfl_xor(m, off));
            float p = act ? __expf(e - m) : 0.f;
            float den = p;
#pragma unroll
            for (int off = 32; off; off >>= 1) den += __shfl_xor(den, off);
            float cs = (p / den) * ssl;
            float Ss = cs;
#pragma unroll
            for (int off = 32; off; off >>= 1) Ss += __shfl_xor(Ss, off);
            S128 = 128.f * Ss;

            int nit = (sdeg + 3) >> 2;
            for (int it = 0; it < nit; ++it) {
                int ei = it * 4 + eg;
                int tt = __shfl(t, ei);
                float cc = __shfl(cs, ei);
                if (ei < sdeg) {
                    uint2 v = *(const uint2*)(xj + (size_t)tt * OUT_DIM);
                    acc[0] += cc * byf(v.x, 0);
                    acc[1] += cc * byf(v.x, 8);
                    acc[2] += cc * byf(v.x, 16);
                    acc[3] += cc * byf(v.x, 24);
                    acc[4] += cc * byf(v.y, 0);
                    acc[5] += cc * byf(v.y, 8);
                    acc[6] += cc * byf(v.y, 16);
                    acc[7] += cc * byf(v.y, 24);
                }
            }
        } else if (sdeg > 64) {
            float m = -INFINITY;
            for (int j = slo + lane; j < shi; j += 64) {
                int t = edge_t[j];
                float e = si + sdst[t];
                e = (e > 0.f) ? e : 0.2f * e;
                m = fmaxf(m, e);
            }
#pragma unroll
            for (int off = 32; off; off >>= 1) m = fmaxf(m, __shfl_xor(m, off));
            float den = 0.f, sS = 0.f;
            for (int j = slo + lane; j < shi; j += 64) {
                int t = edge_t[j];
                float e = si + sdst[t];
                e = (e > 0.f) ? e : 0.2f * e;
                float p = __expf(e - m);
                den += p;
                sS = fmaf(p, ssx[t], sS);
            }
#pragma unroll
            for (int off = 32; off; off >>= 1) {
                den += __shfl_xor(den, off);
                sS  += __shfl_xor(sS, off);
            }
            const float invden = 1.f / den;
            S128 = 128.f * sS * invden;

            for (int jj = slo; jj < shi; jj += 4) {
                int ei = jj + eg;
                if (ei < shi) {
                    int tt = edge_t[ei];
                    float e = si + sdst[tt];
                    e = (e > 0.f) ? e : 0.2f * e;
                    float cc = __expf(e - m) * invden * ssx[tt];
                    uint2 v = *(const uint2*)(xj + (size_t)tt * OUT_DIM);
                    acc[0] += cc * byf(v.x, 0);
                    acc[1] += cc * byf(v.x, 8);
                    acc[2] += cc * byf(v.x, 16);
                    acc[3] += cc * byf(v.x, 24);
                    acc[4] += cc * byf(v.y, 0);
                    acc[5] += cc * byf(v.y, 8);
                    acc[6] += cc * byf(v.y, 16);
                    acc[7] += cc * byf(v.y, 24);
                }
            }
        }

#pragma unroll
        for (int d = 0; d < 8; d++) acc[d] += __shfl_xor(acc[d], 16);
#pragma unroll
        for (int d = 0; d < 8; d++) acc[d] += __shfl_xor(acc[d], 32);

        if (lane < 16) {
            float ssi = ssx[i];
            float r0 = -S128 - 128.f * ssi;
            uint2 rv = *(const uint2*)(xq + (size_t)i * OUT_DIM + j16 * 8);
            float o[8];
            o[0] = fmaf(ssi, byf(rv.x, 0),  acc[0] + r0);
            o[1] = fmaf(ssi, byf(rv.x, 8),  acc[1] + r0);
            o[2] = fmaf(ssi, byf(rv.x, 16), acc[2] + r0);
            o[3] = fmaf(ssi, byf(rv.x, 24), acc[3] + r0);
            o[4] = fmaf(ssi, byf(rv.y, 0),  acc[4] + r0);
            o[5] = fmaf(ssi, byf(rv.y, 8),  acc[5] + r0);
            o[6] = fmaf(ssi, byf(rv.y, 16), acc[6] + r0);
            o[7] = fmaf(ssi, byf(rv.y, 24), acc[7] + r0);
#pragma unroll
            for (int d = 0; d < 8; d++)
                o[d] = (o[d] > 0.f) ? o[d] : __expf(o[d]) - 1.f;
            float* dst = out + (size_t)i * OUT_DIM + j16 * 8;
            *(float4*)(dst)     = make_float4(o[0], o[1], o[2], o[3]);
            *(float4*)(dst + 4) = make_float4(o[4], o[5], o[6], o[7]);
        }
    }
}

// ---------------------------------------------------------------------------
extern "C" void kernel_launch(void* const* d_in, const int* in_sizes, int n_in,
                              void* d_out, int out_size, void* d_ws, size_t ws_size,
                              hipStream_t stream)
{
    const float* input  = (const float*)d_in[0];
    const float* W      = (const float*)d_in[1];
    const float* a      = (const float*)d_in[2];
    const int*   triple = (const int*)d_in[3];
    const int N = in_sizes[0] / IN_DIM;
    const int E = in_sizes[3] / 3;
    float* out = (float*)d_out;

    const int NBC = (N + BNODES - 1) >> BSHIFT;

    char* p = (char*)d_ws;
    auto carve = [&](size_t bytes) {
        char* q = p;
        p += (bytes + 15) & ~(size_t)15;
        return q;
    };
    u8*   xq        = (u8*)carve((size_t)N * OUT_DIM);
    u16*  Wt        = (u16*)carve((size_t)IN_DIM * OUT_DIM * sizeof(u16));
    float* ssx      = (float*)carve((size_t)N * sizeof(float));
    float* ssrc     = (float*)carve((size_t)N * sizeof(float));
    float* sdst     = (float*)carve((size_t)N * sizeof(float));
    int*  startp    = (int*)carve((size_t)(N + 1) * sizeof(int));
    int*  coarse_cur= (int*)carve(256 * sizeof(int));
    int*  edge_t    = (int*)carve((size_t)E * sizeof(int));
    uint2* pairs    = (uint2*)carve((size_t)NBC * CAP * sizeof(uint2));

    const int nScat = (E + 256 * EPT - 1) / (256 * EPT);
    const int nGemm = (N + BM - 1) / BM;

    hipMemsetAsync(coarse_cur, 0, 256 * sizeof(int), stream);
    wt_kernel<<<IN_DIM, OUT_DIM, 0, stream>>>(W, Wt);
    gemm_scatter_kernel<<<nScat + nGemm, 256, 0, stream>>>(
        input, Wt, a, xq, ssx, ssrc, sdst, triple, coarse_cur, pairs, N, E, NBC, nScat);
    bucket_csr_kernel<<<NBC, BNODES, 0, stream>>>(pairs, coarse_cur, startp, edge_t, N, E, NBC);
    aggregate_kernel<<<(N + 7) / 8, 256, 0, stream>>>(xq, ssx, ssrc, sdst, startp, edge_t, out, N);
}

// Round 13
// 115.674 us; speedup vs baseline: 3.6545x; 1.0939x over previous
//
#include <hip/hip_runtime.h>
#include <hip/hip_bf16.h>
#include <math.h>

#define IN_DIM 128
#define OUT_DIM 128
#define BM 64

#define BSHIFT 9            // nodes per coarse bucket = 512
#define BNODES 512
#define CAP 12288           // pair capacity per coarse bucket region (= 24*512)
#define EPT 16              // edges per thread in coarse_scatter
#define PPT 24              // pairs per thread in bucket_csr (CAP/BNODES)

typedef short bf16x8s __attribute__((ext_vector_type(8)));
typedef float f32x4 __attribute__((ext_vector_type(4)));
typedef unsigned short u16;
typedef unsigned char u8;

__device__ inline unsigned int rne_hi(float f) {
    unsigned int u = __float_as_uint(f);
    return u + 0x7fffu + ((u >> 16) & 1u);   // high 16 bits = RNE bf16
}
__device__ inline unsigned int pack_bf16x2(float lo, float hi) {
    return (rne_hi(lo) >> 16) | (rne_hi(hi) & 0xffff0000u);
}
__device__ inline float byf(unsigned int u, int sh) {
    return (float)((u >> sh) & 0xffu);       // -> v_cvt_f32_ubyteN
}

// ---------------------------------------------------------------------------
// K0: transpose + convert W [k][c] fp32 -> Wt bf16 [c][k]
// ---------------------------------------------------------------------------
__global__ void wt_kernel(const float* __restrict__ W, u16* __restrict__ Wt)
{
    int k = blockIdx.x;
    int c = threadIdx.x;
    Wt[c * IN_DIM + k] = (u16)(rne_hi(W[k * OUT_DIM + c]) >> 16);
}

// ---------------------------------------------------------------------------
// K1: FUSED gemm + coarse_scatter. Gemm epilogue row-quantizes x to int8
// (biased by 128) with per-row scale ssx = rowmax/127.
// ---------------------------------------------------------------------------
__global__ __launch_bounds__(256) void gemm_scatter_kernel(
    const float* __restrict__ in, const u16* __restrict__ WtG,
    const float* __restrict__ a, u8* __restrict__ xq, float* __restrict__ ssx,
    float* __restrict__ ssrc, float* __restrict__ sdst,
    const int* __restrict__ triple, int* __restrict__ coarse_cur,
    uint2* __restrict__ pairs, int N, int E, int nbc, int nScat)
{
    const int tid = threadIdx.x;

    if ((int)blockIdx.x < nScat) {
        __shared__ int cnt[256];
        __shared__ int base[256];
        const int cbase = blockIdx.x * (256 * EPT);

        cnt[tid] = 0;
        __syncthreads();

        int h[EPT], t[EPT], pos[EPT];
#pragma unroll
        for (int it = 0; it < EPT; ++it) {
            int idx = cbase + it * 256 + tid;
            if (idx < E) {
                h[it] = triple[3 * idx];
                t[it] = triple[3 * idx + 2];
                pos[it] = atomicAdd(&cnt[h[it] >> BSHIFT], 1);
            }
        }
        __syncthreads();
        if (tid < nbc && cnt[tid] > 0)
            base[tid] = tid * CAP + atomicAdd(&coarse_cur[tid], cnt[tid]);
        __syncthreads();
#pragma unroll
        for (int it = 0; it < EPT; ++it) {
            int idx = cbase + it * 256 + tid;
            if (idx < E)
                pairs[base[h[it] >> BSHIFT] + pos[it]] =
                    make_uint2((unsigned)h[it], (unsigned)t[it]);
        }
        return;
    }

    __shared__ u16 Al[BM][IN_DIM + 8];
    __shared__ u16 Wl[OUT_DIM][IN_DIM + 8];

    const int gb   = blockIdx.x - nScat;
    const int lane = tid & 63;
    const int wave = tid >> 6;
    const int rl   = lane & 15;
    const int rgrp = lane >> 4;

    {
        int r = tid >> 1, c0 = (tid & 1) * 64;
        const uint4* src = (const uint4*)(WtG + r * IN_DIM + c0);
        uint4* dst = (uint4*)&Wl[r][c0];
#pragma unroll
        for (int u = 0; u < 8; u++) dst[u] = src[u];
    }
    const long long rowbase = (long long)gb * BM;
    {
#pragma unroll
        for (int u = 0; u < 8; u++) {
            int idx = u * 256 + tid;
            int r = idx >> 5;
            int c = (idx & 31) * 4;
            long long gr = rowbase + r;
            if (gr >= N) gr = N - 1;
            float4 v = *(const float4*)(in + gr * IN_DIM + c);
            *(uint2*)&Al[r][c] = make_uint2(pack_bf16x2(v.x, v.y), pack_bf16x2(v.z, v.w));
        }
    }
    __syncthreads();

    f32x4 acc[8] = {};
#pragma unroll
    for (int ks = 0; ks < 4; ks++) {
        bf16x8s af = *(const bf16x8s*)&Al[wave * 16 + rl][ks * 32 + rgrp * 8];
#pragma unroll
        for (int cb = 0; cb < 8; cb++) {
            bf16x8s bf = *(const bf16x8s*)&Wl[cb * 16 + rl][ks * 32 + rgrp * 8];
            acc[cb] = __builtin_amdgcn_mfma_f32_16x16x32_bf16(af, bf, acc[cb], 0, 0, 0);
        }
    }

    float a_sv[8], a_dv[8];
#pragma unroll
    for (int cb = 0; cb < 8; cb++) {
        a_sv[cb] = a[rl + 16 * cb];
        a_dv[cb] = a[OUT_DIM + rl + 16 * cb];
    }
#pragma unroll
    for (int r = 0; r < 4; r++) {
        long long grow = rowbase + wave * 16 + rgrp * 4 + r;
        float ps = 0.f, pd = 0.f, rm = 0.f;
#pragma unroll
        for (int cb = 0; cb < 8; cb++) {
            float v = acc[cb][r];
            ps += v * a_sv[cb];
            pd += v * a_dv[cb];
            rm = fmaxf(rm, fabsf(v));
        }
#pragma unroll
        for (int off = 1; off < 16; off <<= 1) {
            ps += __shfl_xor(ps, off);
            pd += __shfl_xor(pd, off);
            rm = fmaxf(rm, __shfl_xor(rm, off));
        }
        rm = fmaxf(rm, 1e-20f);
        const float inv = 127.0f / rm;
        if (grow < N) {
#pragma unroll
            for (int cb = 0; cb < 8; cb++)
                xq[grow * OUT_DIM + rl + 16 * cb] =
                    (u8)(int)(fmaf(acc[cb][r], inv, 128.5f));
            if (rl == 0) {
                ssrc[grow] = ps;
                sdst[grow] = pd;
                ssx[grow]  = rm * (1.0f / 127.0f);
            }
        }
    }
}

// ---------------------------------------------------------------------------
// K2: per-bucket CSR build; pairs read ONCE into registers (static 24-slot
// unroll, compile-time indices), then hist/scan/scatter from regs.
// ---------------------------------------------------------------------------
__global__ __launch_bounds__(512) void bucket_csr_kernel(
    const uint2* __restrict__ pairs, const int* __restrict__ coarse_cur,
    int* __restrict__ startp, int* __restrict__ edge_t, int N, int E, int nbc)
{
    __shared__ int cnt[BNODES];
    __shared__ int scn[BNODES];
    __shared__ int cursor[BNODES];
    __shared__ int bsum[256];
    const int b = blockIdx.x;
    const int tid = threadIdx.x;
    const int plo = b * CAP;
    const int psz = coarse_cur[b];

    // ---- load my pairs into registers (static indices) ----
    uint2 myp[PPT];
#pragma unroll
    for (int jj = 0; jj < PPT; ++jj) {
        int idx = jj * BNODES + tid;
        if (idx < psz) myp[jj] = pairs[plo + idx];
    }

    // ---- inline 256-wide inclusive scan of bucket sizes ----
    if (tid < 256) bsum[tid] = (tid < nbc) ? coarse_cur[tid] : 0;
    __syncthreads();
#pragma unroll
    for (int off = 1; off < 256; off <<= 1) {
        int v = 0;
        if (tid < 256 && tid >= off) v = bsum[tid - off];
        __syncthreads();
        if (tid < 256 && tid >= off) bsum[tid] += v;
        __syncthreads();
    }
    const int obase = bsum[b] - psz;

    cnt[tid] = 0;
    __syncthreads();
#pragma unroll
    for (int jj = 0; jj < PPT; ++jj) {
        int idx = jj * BNODES + tid;
        if (idx < psz) atomicAdd(&cnt[myp[jj].x & (BNODES - 1)], 1);
    }
    __syncthreads();
    scn[tid] = cnt[tid];
    __syncthreads();
#pragma unroll
    for (int off = 1; off < BNODES; off <<= 1) {
        int v = (tid >= off) ? scn[tid - off] : 0;
        __syncthreads();
        scn[tid] += v;
        __syncthreads();
    }
    const int excl = scn[tid] - cnt[tid];
    const int node = b * BNODES + tid;
    if (node < N) startp[node] = obase + excl;
    cursor[tid] = obase + excl;
    __syncthreads();
#pragma unroll
    for (int jj = 0; jj < PPT; ++jj) {
        int idx = jj * BNODES + tid;
        if (idx < psz) {
            int pos = atomicAdd(&cursor[myp[jj].x & (BNODES - 1)], 1);
            edge_t[pos] = (int)myp[jj].y;
        }
    }
    if (b == 0 && tid == 0) startp[N] = E;
}

// ---------------------------------------------------------------------------
// K3: aggregation, TWO nodes per wave, int8 gather table. Fast path
// (degMax<=32): static 16-batch unroll with ALL loads issued before all
// FMAs (up to 16 outstanding 512B gathers/wave); scalar guards via
// readfirstlane (degMax is wave-uniform).
// ---------------------------------------------------------------------------
__global__ __launch_bounds__(256) void aggregate_kernel(
    const u8* __restrict__ xq, const float* __restrict__ ssx,
    const float* __restrict__ ssrc, const float* __restrict__ sdst,
    const int* __restrict__ startp, const int* __restrict__ edge_t,
    float* __restrict__ out, int N)
{
    const int wid  = threadIdx.x >> 6;
    const int lane = threadIdx.x & 63;
    const int i0 = (blockIdx.x * 4 + wid) * 2;
    if (i0 >= N) return;
    const int half = lane >> 5;
    const int l32  = lane & 31;
    const int iH   = i0 + half;
    const bool hasH = iH < N;
    const int j16 = lane & 15;

    int lo = 0, hi = 0;
    if (hasH) { lo = startp[iH]; hi = startp[iH + 1]; }
    const int deg = hi - lo;
    const int degO = __shfl_xor(deg, 32);
    const int degMax = __builtin_amdgcn_readfirstlane(max(deg, degO));

    float acc[8];
#pragma unroll
    for (int d = 0; d < 8; d++) acc[d] = 0.f;

    if (degMax <= 32) {
        const float si = hasH ? ssrc[iH] : 0.f;
        bool act = l32 < deg;
        int t = act ? edge_t[lo + l32] : 0;
        float sde = act ? sdst[t] : 0.f;
        float ssl = act ? ssx[t] : 0.f;
        float e = act ? si + sde : -INFINITY;
        e = (e > 0.f) ? e : 0.2f * e;
        float m = e;
#pragma unroll
        for (int off = 16; off; off >>= 1) m = fmaxf(m, __shfl_xor(m, off));
        float p = act ? __expf(e - m) : 0.f;
        float den = p;
#pragma unroll
        for (int off = 16; off; off >>= 1) den += __shfl_xor(den, off);
        float w = (deg > 0) ? p / den : 0.f;
        float cs = w * ssl;
        float Ss = cs;
#pragma unroll
        for (int off = 16; off; off >>= 1) Ss += __shfl_xor(Ss, off);

        const int slot = (lane >> 4) & 1;
        const int srcBase = half << 5;
        const u8* xj = xq + j16 * 8;
        const int nb = (degMax + 1) >> 1;   // scalar (degMax scalar)

        // ---- issue ALL gathers, then ALL FMAs (static reg indices) ----
        uint2 v[16];
        float cc[16];
#pragma unroll
        for (int bb = 0; bb < 16; ++bb) {
            if (bb < nb) {
                int ei = bb * 2 + slot;
                int tt = __shfl(t, srcBase + ei);
                cc[bb] = __shfl(cs, srcBase + ei);
                v[bb] = *(const uint2*)(xj + (size_t)tt * OUT_DIM);
            }
        }
#pragma unroll
        for (int bb = 0; bb < 16; ++bb) {
            if (bb < nb) {
                float c = cc[bb];
                acc[0] += c * byf(v[bb].x, 0);
                acc[1] += c * byf(v[bb].x, 8);
                acc[2] += c * byf(v[bb].x, 16);
                acc[3] += c * byf(v[bb].x, 24);
                acc[4] += c * byf(v[bb].y, 0);
                acc[5] += c * byf(v[bb].y, 8);
                acc[6] += c * byf(v[bb].y, 16);
                acc[7] += c * byf(v[bb].y, 24);
            }
        }

#pragma unroll
        for (int d = 0; d < 8; d++) acc[d] += __shfl_xor(acc[d], 16);

        if (!(lane & 16) && hasH) {
            float ssi = ssx[iH];
            float r0 = -128.f * Ss - 128.f * ssi;
            uint2 rv = *(const uint2*)(xq + (size_t)iH * OUT_DIM + j16 * 8);
            float o[8];
            o[0] = fmaf(ssi, byf(rv.x, 0),  acc[0] + r0);
            o[1] = fmaf(ssi, byf(rv.x, 8),  acc[1] + r0);
            o[2] = fmaf(ssi, byf(rv.x, 16), acc[2] + r0);
            o[3] = fmaf(ssi, byf(rv.x, 24), acc[3] + r0);
            o[4] = fmaf(ssi, byf(rv.y, 0),  acc[4] + r0);
            o[5] = fmaf(ssi, byf(rv.y, 8),  acc[5] + r0);
            o[6] = fmaf(ssi, byf(rv.y, 16), acc[6] + r0);
            o[7] = fmaf(ssi, byf(rv.y, 24), acc[7] + r0);
#pragma unroll
            for (int d = 0; d < 8; d++)
                o[d] = (o[d] > 0.f) ? o[d] : __expf(o[d]) - 1.f;
            float* dst = out + (size_t)iH * OUT_DIM + j16 * 8;
            *(float4*)(dst)     = make_float4(o[0], o[1], o[2], o[3]);
            *(float4*)(dst + 4) = make_float4(o[4], o[5], o[6], o[7]);
        }
        return;
    }

    // ================= rare slow path: full wave per node =================
    const int eg = lane >> 4;
    for (int h = 0; h < 2; ++h) {
        const int i = i0 + h;
        if (i >= N) break;
        const int slo = startp[i];
        const int shi = startp[i + 1];
        const int sdeg = shi - slo;
        const float si = ssrc[i];
        float S128 = 0.f;

#pragma unroll
        for (int d = 0; d < 8; d++) acc[d] = 0.f;
        const u8* xj = xq + j16 * 8;

        if (sdeg > 0 && sdeg <= 64) {
            int j = slo + lane;
            bool act = j < shi;
            int t = act ? edge_t[j] : 0;
            float ssl = act ? ssx[t] : 0.f;
            float e = act ? si + sdst[t] : -INFINITY;
            e = (e > 0.f) ? e : 0.2f * e;
            float m = e;
#pragma unroll
            for (int off = 32; off; off >>= 1) m = fmaxf(m, __shfl_xor(m, off));
            float p = act ? __expf(e - m) : 0.f;
            float den = p;
#pragma unroll
            for (int off = 32; off; off >>= 1) den += __shfl_xor(den, off);
            float cs = (p / den) * ssl;
            float Ss = cs;
#pragma unroll
            for (int off = 32; off; off >>= 1) Ss += __shfl_xor(Ss, off);
            S128 = 128.f * Ss;

            int nit = (sdeg + 3) >> 2;
            for (int it = 0; it < nit; ++it) {
                int ei = it * 4 + eg;
                int tt = __shfl(t, ei);
                float c = __shfl(cs, ei);
                if (ei < sdeg) {
                    uint2 v = *(const uint2*)(xj + (size_t)tt * OUT_DIM);
                    acc[0] += c * byf(v.x, 0);
                    acc[1] += c * byf(v.x, 8);
                    acc[2] += c * byf(v.x, 16);
                    acc[3] += c * byf(v.x, 24);
                    acc[4] += c * byf(v.y, 0);
                    acc[5] += c * byf(v.y, 8);
                    acc[6] += c * byf(v.y, 16);
                    acc[7] += c * byf(v.y, 24);
                }
            }
        } else if (sdeg > 64) {
            float m = -INFINITY;
            for (int j = slo + lane; j < shi; j += 64) {
                int t = edge_t[j];
                float e = si + sdst[t];
                e = (e > 0.f) ? e : 0.2f * e;
                m = fmaxf(m, e);
            }
#pragma unroll
            for (int off = 32; off; off >>= 1) m = fmaxf(m, __shfl_xor(m, off));
            float den = 0.f, sS = 0.f;
            for (int j = slo + lane; j < shi; j += 64) {
                int t = edge_t[j];
                float e = si + sdst[t];
                e = (e > 0.f) ? e : 0.2f * e;
                float p = __expf(e - m);
                den += p;
                sS = fmaf(p, ssx[t], sS);
            }
#pragma unroll
            for (int off = 32; off; off >>= 1) {
                den += __shfl_xor(den, off);
                sS  += __shfl_xor(sS, off);
            }
            const float invden = 1.f / den;
            S128 = 128.f * sS * invden;

            for (int jj = slo; jj < shi; jj += 4) {
                int ei = jj + eg;
                if (ei < shi) {
                    int tt = edge_t[ei];
                    float e = si + sdst[tt];
                    e = (e > 0.f) ? e : 0.2f * e;
                    float c = __expf(e - m) * invden * ssx[tt];
                    uint2 v = *(const uint2*)(xj + (size_t)tt * OUT_DIM);
                    acc[0] += c * byf(v.x, 0);
                    acc[1] += c * byf(v.x, 8);
                    acc[2] += c * byf(v.x, 16);
                    acc[3] += c * byf(v.x, 24);
                    acc[4] += c * byf(v.y, 0);
                    acc[5] += c * byf(v.y, 8);
                    acc[6] += c * byf(v.y, 16);
                    acc[7] += c * byf(v.y, 24);
                }
            }
        }

#pragma unroll
        for (int d = 0; d < 8; d++) acc[d] += __shfl_xor(acc[d], 16);
#pragma unroll
        for (int d = 0; d < 8; d++) acc[d] += __shfl_xor(acc[d], 32);

        if (lane < 16) {
            float ssi = ssx[i];
            float r0 = -S128 - 128.f * ssi;
            uint2 rv = *(const uint2*)(xq + (size_t)i * OUT_DIM + j16 * 8);
            float o[8];
            o[0] = fmaf(ssi, byf(rv.x, 0),  acc[0] + r0);
            o[1] = fmaf(ssi, byf(rv.x, 8),  acc[1] + r0);
            o[2] = fmaf(ssi, byf(rv.x, 16), acc[2] + r0);
            o[3] = fmaf(ssi, byf(rv.x, 24), acc[3] + r0);
            o[4] = fmaf(ssi, byf(rv.y, 0),  acc[4] + r0);
            o[5] = fmaf(ssi, byf(rv.y, 8),  acc[5] + r0);
            o[6] = fmaf(ssi, byf(rv.y, 16), acc[6] + r0);
            o[7] = fmaf(ssi, byf(rv.y, 24), acc[7] + r0);
#pragma unroll
            for (int d = 0; d < 8; d++)
                o[d] = (o[d] > 0.f) ? o[d] : __expf(o[d]) - 1.f;
            float* dst = out + (size_t)i * OUT_DIM + j16 * 8;
            *(float4*)(dst)     = make_float4(o[0], o[1], o[2], o[3]);
            *(float4*)(dst + 4) = make_float4(o[4], o[5], o[6], o[7]);
        }
    }
}

// ---------------------------------------------------------------------------
extern "C" void kernel_launch(void* const* d_in, const int* in_sizes, int n_in,
                              void* d_out, int out_size, void* d_ws, size_t ws_size,
                              hipStream_t stream)
{
    const float* input  = (const float*)d_in[0];
    const float* W      = (const float*)d_in[1];
    const float* a      = (const float*)d_in[2];
    const int*   triple = (const int*)d_in[3];
    const int N = in_sizes[0] / IN_DIM;
    const int E = in_sizes[3] / 3;
    float* out = (float*)d_out;

    const int NBC = (N + BNODES - 1) >> BSHIFT;

    char* p = (char*)d_ws;
    auto carve = [&](size_t bytes) {
        char* q = p;
        p += (bytes + 15) & ~(size_t)15;
        return q;
    };
    u8*   xq        = (u8*)carve((size_t)N * OUT_DIM);
    u16*  Wt        = (u16*)carve((size_t)IN_DIM * OUT_DIM * sizeof(u16));
    float* ssx      = (float*)carve((size_t)N * sizeof(float));
    float* ssrc     = (float*)carve((size_t)N * sizeof(float));
    float* sdst     = (float*)carve((size_t)N * sizeof(float));
    int*  startp    = (int*)carve((size_t)(N + 1) * sizeof(int));
    int*  coarse_cur= (int*)carve(256 * sizeof(int));
    int*  edge_t    = (int*)carve((size_t)E * sizeof(int));
    uint2* pairs    = (uint2*)carve((size_t)NBC * CAP * sizeof(uint2));

    const int nScat = (E + 256 * EPT - 1) / (256 * EPT);
    const int nGemm = (N + BM - 1) / BM;

    hipMemsetAsync(coarse_cur, 0, 256 * sizeof(int), stream);
    wt_kernel<<<IN_DIM, OUT_DIM, 0, stream>>>(W, Wt);
    gemm_scatter_kernel<<<nScat + nGemm, 256, 0, stream>>>(
        input, Wt, a, xq, ssx, ssrc, sdst, triple, coarse_cur, pairs, N, E, NBC, nScat);
    bucket_csr_kernel<<<NBC, BNODES, 0, stream>>>(pairs, coarse_cur, startp, edge_t, N, E, NBC);
    aggregate_kernel<<<(N + 7) / 8, 256, 0, stream>>>(xq, ssx, ssrc, sdst, startp, edge_t, out, N);
}

// Round 14
// 107.691 us; speedup vs baseline: 3.9255x; 1.0741x over previous
//
#include <hip/hip_runtime.h>
#include <hip/hip_bf16.h>
#include <math.h>

#define IN_DIM 128
#define OUT_DIM 128
#define BM 64

#define BSHIFT 9            // nodes per coarse bucket = 512
#define BNODES 512
#define CAP 12288           // pair capacity per coarse bucket region (= 24*512)
#define EPT 16              // edges per thread in coarse_scatter
#define PPT 24              // pairs per thread in bucket_csr (CAP/BNODES)

typedef short bf16x8s __attribute__((ext_vector_type(8)));
typedef float f32x4 __attribute__((ext_vector_type(4)));
typedef unsigned short u16;
typedef unsigned char u8;
typedef unsigned int u32;

__device__ inline unsigned int rne_hi(float f) {
    unsigned int u = __float_as_uint(f);
    return u + 0x7fffu + ((u >> 16) & 1u);   // high 16 bits = RNE bf16
}
__device__ inline unsigned int pack_bf16x2(float lo, float hi) {
    return (rne_hi(lo) >> 16) | (rne_hi(hi) & 0xffff0000u);
}
__device__ inline float byf(unsigned int u, int sh) {
    return (float)((u >> sh) & 0xffu);       // -> v_cvt_f32_ubyteN
}

// ---------------------------------------------------------------------------
// K0: transpose + convert W [k][c] fp32 -> Wt bf16 [c][k]; zero-init the
// coarse-bucket size counters (fused: saves the memset dispatch).
// ---------------------------------------------------------------------------
__global__ void wt_kernel(const float* __restrict__ W, u16* __restrict__ Wt,
                          int* __restrict__ coarse_cur)
{
    int k = blockIdx.x;
    int c = threadIdx.x;
    int ii = k * OUT_DIM + c;
    if (ii < 256) coarse_cur[ii] = 0;
    Wt[c * IN_DIM + k] = (u16)(rne_hi(W[ii]) >> 16);
}

// ---------------------------------------------------------------------------
// K1: FUSED gemm + coarse_scatter. Gemm epilogue row-quantizes x to int8
// (biased 128, scale ssx=rowmax/127) and writes (sdst,ssx) as ONE float2.
// Scatter packs (h_local<<17 | t) into u32 pairs.
// ---------------------------------------------------------------------------
__global__ __launch_bounds__(256) void gemm_scatter_kernel(
    const float* __restrict__ in, const u16* __restrict__ WtG,
    const float* __restrict__ a, u8* __restrict__ xq,
    float* __restrict__ ssrc, float2* __restrict__ sds,
    const int* __restrict__ triple, int* __restrict__ coarse_cur,
    u32* __restrict__ pairs, int N, int E, int nbc, int nScat)
{
    const int tid = threadIdx.x;

    if ((int)blockIdx.x < nScat) {
        __shared__ int cnt[256];
        __shared__ int base[256];
        const int cbase = blockIdx.x * (256 * EPT);

        cnt[tid] = 0;
        __syncthreads();

        int h[EPT], t[EPT], pos[EPT];
#pragma unroll
        for (int it = 0; it < EPT; ++it) {
            int idx = cbase + it * 256 + tid;
            if (idx < E) {
                h[it] = triple[3 * idx];
                t[it] = triple[3 * idx + 2];
                pos[it] = atomicAdd(&cnt[h[it] >> BSHIFT], 1);
            }
        }
        __syncthreads();
        if (tid < nbc && cnt[tid] > 0)
            base[tid] = tid * CAP + atomicAdd(&coarse_cur[tid], cnt[tid]);
        __syncthreads();
#pragma unroll
        for (int it = 0; it < EPT; ++it) {
            int idx = cbase + it * 256 + tid;
            if (idx < E)
                pairs[base[h[it] >> BSHIFT] + pos[it]] =
                    ((u32)(h[it] & (BNODES - 1)) << 17) | (u32)t[it];
        }
        return;
    }

    __shared__ u16 Al[BM][IN_DIM + 8];
    __shared__ u16 Wl[OUT_DIM][IN_DIM + 8];

    const int gb   = blockIdx.x - nScat;
    const int lane = tid & 63;
    const int wave = tid >> 6;
    const int rl   = lane & 15;
    const int rgrp = lane >> 4;

    {
        int r = tid >> 1, c0 = (tid & 1) * 64;
        const uint4* src = (const uint4*)(WtG + r * IN_DIM + c0);
        uint4* dst = (uint4*)&Wl[r][c0];
#pragma unroll
        for (int u = 0; u < 8; u++) dst[u] = src[u];
    }
    const long long rowbase = (long long)gb * BM;
    {
#pragma unroll
        for (int u = 0; u < 8; u++) {
            int idx = u * 256 + tid;
            int r = idx >> 5;
            int c = (idx & 31) * 4;
            long long gr = rowbase + r;
            if (gr >= N) gr = N - 1;
            float4 v = *(const float4*)(in + gr * IN_DIM + c);
            *(uint2*)&Al[r][c] = make_uint2(pack_bf16x2(v.x, v.y), pack_bf16x2(v.z, v.w));
        }
    }
    __syncthreads();

    f32x4 acc[8] = {};
#pragma unroll
    for (int ks = 0; ks < 4; ks++) {
        bf16x8s af = *(const bf16x8s*)&Al[wave * 16 + rl][ks * 32 + rgrp * 8];
#pragma unroll
        for (int cb = 0; cb < 8; cb++) {
            bf16x8s bf = *(const bf16x8s*)&Wl[cb * 16 + rl][ks * 32 + rgrp * 8];
            acc[cb] = __builtin_amdgcn_mfma_f32_16x16x32_bf16(af, bf, acc[cb], 0, 0, 0);
        }
    }

    float a_sv[8], a_dv[8];
#pragma unroll
    for (int cb = 0; cb < 8; cb++) {
        a_sv[cb] = a[rl + 16 * cb];
        a_dv[cb] = a[OUT_DIM + rl + 16 * cb];
    }
#pragma unroll
    for (int r = 0; r < 4; r++) {
        long long grow = rowbase + wave * 16 + rgrp * 4 + r;
        float ps = 0.f, pd = 0.f, rm = 0.f;
#pragma unroll
        for (int cb = 0; cb < 8; cb++) {
            float v = acc[cb][r];
            ps += v * a_sv[cb];
            pd += v * a_dv[cb];
            rm = fmaxf(rm, fabsf(v));
        }
#pragma unroll
        for (int off = 1; off < 16; off <<= 1) {
            ps += __shfl_xor(ps, off);
            pd += __shfl_xor(pd, off);
            rm = fmaxf(rm, __shfl_xor(rm, off));
        }
        rm = fmaxf(rm, 1e-20f);
        const float inv = 127.0f / rm;
        if (grow < N) {
#pragma unroll
            for (int cb = 0; cb < 8; cb++)
                xq[grow * OUT_DIM + rl + 16 * cb] =
                    (u8)(int)(fmaf(acc[cb][r], inv, 128.5f));
            if (rl == 0) {
                ssrc[grow] = ps;
                sds[grow]  = make_float2(pd, rm * (1.0f / 127.0f));
            }
        }
    }
}

// ---------------------------------------------------------------------------
// K2: per-bucket CSR build. Pairs (packed u32) read ONCE into registers;
// wave-shuffle scans (no 9-round barrier scan); obase via block reduce.
// ---------------------------------------------------------------------------
__global__ __launch_bounds__(512) void bucket_csr_kernel(
    const u32* __restrict__ pairs, const int* __restrict__ coarse_cur,
    int* __restrict__ startp, int* __restrict__ edge_t, int N, int E, int nbc)
{
    __shared__ int cnt[BNODES];
    __shared__ int cursor[BNODES];
    __shared__ int wsum[8];
    __shared__ int obase_s;
    const int b = blockIdx.x;
    const int tid = threadIdx.x;
    const int wv  = tid >> 6;
    const int ln  = tid & 63;
    const int plo = b * CAP;
    const int psz = coarse_cur[b];

    // ---- load my pairs into registers (static indices) ----
    u32 myp[PPT];
#pragma unroll
    for (int jj = 0; jj < PPT; ++jj) {
        int idx = jj * BNODES + tid;
        if (idx < psz) myp[jj] = pairs[plo + idx];
    }

    // ---- obase = sum of bucket sizes < b (block reduce) ----
    {
        int v = (tid < b) ? coarse_cur[tid] : 0;   // b <= 255 < 512
#pragma unroll
        for (int off = 32; off; off >>= 1) v += __shfl_xor(v, off);
        if (ln == 0) wsum[wv] = v;
        __syncthreads();
        if (tid == 0) {
            int s = 0;
#pragma unroll
            for (int w = 0; w < 8; w++) s += wsum[w];
            obase_s = s;
        }
    }

    cnt[tid] = 0;
    __syncthreads();
#pragma unroll
    for (int jj = 0; jj < PPT; ++jj) {
        int idx = jj * BNODES + tid;
        if (idx < psz) atomicAdd(&cnt[myp[jj] >> 17], 1);
    }
    __syncthreads();

    // ---- block-wide exclusive scan of cnt via wave shuffles ----
    const int myCnt = cnt[tid];
    int sc = myCnt;
#pragma unroll
    for (int off = 1; off < 64; off <<= 1) {
        int u = __shfl_up(sc, off);
        if (ln >= off) sc += u;
    }
    if (ln == 63) wsum[wv] = sc;
    __syncthreads();
    int wbase = 0;
    {
        // thread 0 of each wave computes its wave's base
#pragma unroll
        for (int w = 0; w < 8; w++) {
            int s = wsum[w];
            if (w < wv) wbase += s;
        }
    }
    const int obase = obase_s;
    const int excl = obase + wbase + sc - myCnt;
    const int node = b * BNODES + tid;
    if (node < N) startp[node] = excl;
    cursor[tid] = excl;
    __syncthreads();
#pragma unroll
    for (int jj = 0; jj < PPT; ++jj) {
        int idx = jj * BNODES + tid;
        if (idx < psz) {
            u32 p = myp[jj];
            int pos = atomicAdd(&cursor[p >> 17], 1);
            edge_t[pos] = (int)(p & 0x1FFFFu);
        }
    }
    if (b == 0 && tid == 0) startp[N] = E;
}

// ---------------------------------------------------------------------------
// K3: aggregation, TWO nodes per wave, int8 gather table. Fast path
// (degMax<=32): static 16-batch unroll, all loads before all FMAs.
// (sdst,ssx) fetched as one float2 (halves score-phase requests).
// ---------------------------------------------------------------------------
__global__ __launch_bounds__(256) void aggregate_kernel(
    const u8* __restrict__ xq, const float* __restrict__ ssrc,
    const float2* __restrict__ sds, const int* __restrict__ startp,
    const int* __restrict__ edge_t, float* __restrict__ out, int N)
{
    const int wid  = threadIdx.x >> 6;
    const int lane = threadIdx.x & 63;
    const int i0 = (blockIdx.x * 4 + wid) * 2;
    if (i0 >= N) return;
    const int half = lane >> 5;
    const int l32  = lane & 31;
    const int iH   = i0 + half;
    const bool hasH = iH < N;
    const int j16 = lane & 15;

    int lo = 0, hi = 0;
    if (hasH) { lo = startp[iH]; hi = startp[iH + 1]; }
    const int deg = hi - lo;
    const int degO = __shfl_xor(deg, 32);
    const int degMax = __builtin_amdgcn_readfirstlane(max(deg, degO));

    float acc[8];
#pragma unroll
    for (int d = 0; d < 8; d++) acc[d] = 0.f;

    if (degMax <= 32) {
        const float si = hasH ? ssrc[iH] : 0.f;
        bool act = l32 < deg;
        int t = act ? edge_t[lo + l32] : 0;
        float2 sv = act ? sds[t] : make_float2(0.f, 0.f);
        float e = act ? si + sv.x : -INFINITY;
        e = (e > 0.f) ? e : 0.2f * e;
        float m = e;
#pragma unroll
        for (int off = 16; off; off >>= 1) m = fmaxf(m, __shfl_xor(m, off));
        float p = act ? __expf(e - m) : 0.f;
        float den = p;
#pragma unroll
        for (int off = 16; off; off >>= 1) den += __shfl_xor(den, off);
        float w = (deg > 0) ? p / den : 0.f;
        float cs = w * sv.y;
        float Ss = cs;
#pragma unroll
        for (int off = 16; off; off >>= 1) Ss += __shfl_xor(Ss, off);

        const int slot = (lane >> 4) & 1;
        const int srcBase = half << 5;
        const u8* xj = xq + j16 * 8;
        const int nb = (degMax + 1) >> 1;   // scalar

        uint2 v[16];
        float cc[16];
#pragma unroll
        for (int bb = 0; bb < 16; ++bb) {
            if (bb < nb) {
                int ei = bb * 2 + slot;
                int tt = __shfl(t, srcBase + ei);
                cc[bb] = __shfl(cs, srcBase + ei);
                v[bb] = *(const uint2*)(xj + (size_t)tt * OUT_DIM);
            }
        }
#pragma unroll
        for (int bb = 0; bb < 16; ++bb) {
            if (bb < nb) {
                float c = cc[bb];
                acc[0] += c * byf(v[bb].x, 0);
                acc[1] += c * byf(v[bb].x, 8);
                acc[2] += c * byf(v[bb].x, 16);
                acc[3] += c * byf(v[bb].x, 24);
                acc[4] += c * byf(v[bb].y, 0);
                acc[5] += c * byf(v[bb].y, 8);
                acc[6] += c * byf(v[bb].y, 16);
                acc[7] += c * byf(v[bb].y, 24);
            }
        }

#pragma unroll
        for (int d = 0; d < 8; d++) acc[d] += __shfl_xor(acc[d], 16);

        if (!(lane & 16) && hasH) {
            float ssi = sds[iH].y;
            float r0 = -128.f * Ss - 128.f * ssi;
            uint2 rv = *(const uint2*)(xq + (size_t)iH * OUT_DIM + j16 * 8);
            float o[8];
            o[0] = fmaf(ssi, byf(rv.x, 0),  acc[0] + r0);
            o[1] = fmaf(ssi, byf(rv.x, 8),  acc[1] + r0);
            o[2] = fmaf(ssi, byf(rv.x, 16), acc[2] + r0);
            o[3] = fmaf(ssi, byf(rv.x, 24), acc[3] + r0);
            o[4] = fmaf(ssi, byf(rv.y, 0),  acc[4] + r0);
            o[5] = fmaf(ssi, byf(rv.y, 8),  acc[5] + r0);
            o[6] = fmaf(ssi, byf(rv.y, 16), acc[6] + r0);
            o[7] = fmaf(ssi, byf(rv.y, 24), acc[7] + r0);
#pragma unroll
            for (int d = 0; d < 8; d++)
                o[d] = (o[d] > 0.f) ? o[d] : __expf(o[d]) - 1.f;
            float* dst = out + (size_t)iH * OUT_DIM + j16 * 8;
            *(float4*)(dst)     = make_float4(o[0], o[1], o[2], o[3]);
            *(float4*)(dst + 4) = make_float4(o[4], o[5], o[6], o[7]);
        }
        return;
    }

    // ================= rare slow path: full wave per node =================
    const int eg = lane >> 4;
    for (int h = 0; h < 2; ++h) {
        const int i = i0 + h;
        if (i >= N) break;
        const int slo = startp[i];
        const int shi = startp[i + 1];
        const int sdeg = shi - slo;
        const float si = ssrc[i];
        float S128 = 0.f;

#pragma unroll
        for (int d = 0; d < 8; d++) acc[d] = 0.f;
        const u8* xj = xq + j16 * 8;

        if (sdeg > 0 && sdeg <= 64) {
            int j = slo + lane;
            bool act = j < shi;
            int t = act ? edge_t[j] : 0;
            float2 sv = act ? sds[t] : make_float2(0.f, 0.f);
            float e = act ? si + sv.x : -INFINITY;
            e = (e > 0.f) ? e : 0.2f * e;
            float m = e;
#pragma unroll
            for (int off = 32; off; off >>= 1) m = fmaxf(m, __shfl_xor(m, off));
            float p = act ? __expf(e - m) : 0.f;
            float den = p;
#pragma unroll
            for (int off = 32; off; off >>= 1) den += __shfl_xor(den, off);
            float cs = (p / den) * sv.y;
            float Ss = cs;
#pragma unroll
            for (int off = 32; off; off >>= 1) Ss += __shfl_xor(Ss, off);
            S128 = 128.f * Ss;

            int nit = (sdeg + 3) >> 2;
            for (int it = 0; it < nit; ++it) {
                int ei = it * 4 + eg;
                int tt = __shfl(t, ei);
                float c = __shfl(cs, ei);
                if (ei < sdeg) {
                    uint2 v = *(const uint2*)(xj + (size_t)tt * OUT_DIM);
                    acc[0] += c * byf(v.x, 0);
                    acc[1] += c * byf(v.x, 8);
                    acc[2] += c * byf(v.x, 16);
                    acc[3] += c * byf(v.x, 24);
                    acc[4] += c * byf(v.y, 0);
                    acc[5] += c * byf(v.y, 8);
                    acc[6] += c * byf(v.y, 16);
                    acc[7] += c * byf(v.y, 24);
                }
            }
        } else if (sdeg > 64) {
            float m = -INFINITY;
            for (int j = slo + lane; j < shi; j += 64) {
                int t = edge_t[j];
                float e = si + sds[t].x;
                e = (e > 0.f) ? e : 0.2f * e;
                m = fmaxf(m, e);
            }
#pragma unroll
            for (int off = 32; off; off >>= 1) m = fmaxf(m, __shfl_xor(m, off));
            float den = 0.f, sS = 0.f;
            for (int j = slo + lane; j < shi; j += 64) {
                int t = edge_t[j];
                float2 sv = sds[t];
                float e = si + sv.x;
                e = (e > 0.f) ? e : 0.2f * e;
                float p = __expf(e - m);
                den += p;
                sS = fmaf(p, sv.y, sS);
            }
#pragma unroll
            for (int off = 32; off; off >>= 1) {
                den += __shfl_xor(den, off);
                sS  += __shfl_xor(sS, off);
            }
            const float invden = 1.f / den;
            S128 = 128.f * sS * invden;

            for (int jj = slo; jj < shi; jj += 4) {
                int ei = jj + eg;
                if (ei < shi) {
                    int tt = edge_t[ei];
                    float2 sv = sds[tt];
                    float e = si + sv.x;
                    e = (e > 0.f) ? e : 0.2f * e;
                    float c = __expf(e - m) * invden * sv.y;
                    uint2 v = *(const uint2*)(xj + (size_t)tt * OUT_DIM);
                    acc[0] += c * byf(v.x, 0);
                    acc[1] += c * byf(v.x, 8);
                    acc[2] += c * byf(v.x, 16);
                    acc[3] += c * byf(v.x, 24);
                    acc[4] += c * byf(v.y, 0);
                    acc[5] += c * byf(v.y, 8);
                    acc[6] += c * byf(v.y, 16);
                    acc[7] += c * byf(v.y, 24);
                }
            }
        }

#pragma unroll
        for (int d = 0; d < 8; d++) acc[d] += __shfl_xor(acc[d], 16);
#pragma unroll
        for (int d = 0; d < 8; d++) acc[d] += __shfl_xor(acc[d], 32);

        if (lane < 16) {
            float ssi = sds[i].y;
            float r0 = -S128 - 128.f * ssi;
            uint2 rv = *(const uint2*)(xq + (size_t)i * OUT_DIM + j16 * 8);
            float o[8];
            o[0] = fmaf(ssi, byf(rv.x, 0),  acc[0] + r0);
            o[1] = fmaf(ssi, byf(rv.x, 8),  acc[1] + r0);
            o[2] = fmaf(ssi, byf(rv.x, 16), acc[2] + r0);
            o[3] = fmaf(ssi, byf(rv.x, 24), acc[3] + r0);
            o[4] = fmaf(ssi, byf(rv.y, 0),  acc[4] + r0);
            o[5] = fmaf(ssi, byf(rv.y, 8),  acc[5] + r0);
            o[6] = fmaf(ssi, byf(rv.y, 16), acc[6] + r0);
            o[7] = fmaf(ssi, byf(rv.y, 24), acc[7] + r0);
#pragma unroll
            for (int d = 0; d < 8; d++)
                o[d] = (o[d] > 0.f) ? o[d] : __expf(o[d]) - 1.f;
            float* dst = out + (size_t)i * OUT_DIM + j16 * 8;
            *(float4*)(dst)     = make_float4(o[0], o[1], o[2], o[3]);
            *(float4*)(dst + 4) = make_float4(o[4], o[5], o[6], o[7]);
        }
    }
}

// ---------------------------------------------------------------------------
extern "C" void kernel_launch(void* const* d_in, const int* in_sizes, int n_in,
                              void* d_out, int out_size, void* d_ws, size_t ws_size,
                              hipStream_t stream)
{
    const float* input  = (const float*)d_in[0];
    const float* W      = (const float*)d_in[1];
    const float* a      = (const float*)d_in[2];
    const int*   triple = (const int*)d_in[3];
    const int N = in_sizes[0] / IN_DIM;
    const int E = in_sizes[3] / 3;
    float* out = (float*)d_out;

    const int NBC = (N + BNODES - 1) >> BSHIFT;

    char* p = (char*)d_ws;
    auto carve = [&](size_t bytes) {
        char* q = p;
        p += (bytes + 15) & ~(size_t)15;
        return q;
    };
    u8*    xq        = (u8*)carve((size_t)N * OUT_DIM);
    u16*   Wt        = (u16*)carve((size_t)IN_DIM * OUT_DIM * sizeof(u16));
    float* ssrc      = (float*)carve((size_t)N * sizeof(float));
    float2* sds      = (float2*)carve((size_t)N * sizeof(float2));
    int*   startp    = (int*)carve((size_t)(N + 1) * sizeof(int));
    int*   coarse_cur= (int*)carve(256 * sizeof(int));
    int*   edge_t    = (int*)carve((size_t)E * sizeof(int));
    u32*   pairs     = (u32*)carve((size_t)NBC * CAP * sizeof(u32));

    const int nScat = (E + 256 * EPT - 1) / (256 * EPT);
    const int nGemm = (N + BM - 1) / BM;

    wt_kernel<<<IN_DIM, OUT_DIM, 0, stream>>>(W, Wt, coarse_cur);
    gemm_scatter_kernel<<<nScat + nGemm, 256, 0, stream>>>(
        input, Wt, a, xq, ssrc, sds, triple, coarse_cur, pairs, N, E, NBC, nScat);
    bucket_csr_kernel<<<NBC, BNODES, 0, stream>>>(pairs, coarse_cur, startp, edge_t, N, E, NBC);
    aggregate_kernel<<<(N + 7) / 8, 256, 0, stream>>>(xq, ssrc, sds, startp, edge_t, out, N);
}